// Round 3
// baseline (102.697 us; speedup 1.0000x reference)
//
#include <hip/hip_runtime.h>

// Two-level connected components: per-tile union-find in LDS driven by
// 64-bit row masks (one wave == one 64-px row, __ballot builds the bitmap),
// then global border merges, then a root-walk relabel.
//
// Label semantics: out = MULT - min(local linear index over 8-conn component)
// for foreground, 0 for background.
//
// parent[] encoding: -1 = background, >=0 = union-find parent (global pixel
// index). parent[p] <= p invariant guarantees termination; every stored value
// is a true ancestor, so stale non-atomic reads remain safe.

constexpr int W_DIM = 2048;
constexpr int H_DIM = 2048;
constexpr int MULT  = W_DIM * H_DIM;        // 2^22 pixels per image
constexpr int TILE  = 64;
constexpr int TPX   = TILE * TILE;          // 4096 pixels per tile
constexpr int BLK   = 256;                  // 4 waves
constexpr int TILES_PER_IMG = MULT / TPX;   // 1024
constexpr int NB    = (H_DIM / TILE) - 1;   // 31 interior boundaries per dim

__device__ __forceinline__ int find_root(const int* p, int v) {
    int q = p[v];
    while (q != v) { v = q; q = p[v]; }
    return v;
}

// atomicMin-based concurrent union; works identically on LDS and global.
__device__ __forceinline__ void merge_uf(int* p, int a, int b) {
    while (true) {
        a = find_root(p, a);
        b = find_root(p, b);
        if (a == b) return;
        if (a < b) { int t = a; a = b; b = t; }  // a > b
        int old = atomicMin(&p[a], b);
        if (old == a) return;                    // a was root; linked under b
        a = old;                                 // displaced; retry from old
    }
}

// Phase 1: per-tile local CCL in LDS; write global parent (bg = -1).
// One wave handles one 64-px row at a time: lane l <-> column l.
__global__ __launch_bounds__(BLK) void cc_local(const float* __restrict__ x,
                                                int* __restrict__ parent) {
    __shared__ int lp[TPX];
    __shared__ unsigned long long rowmask[TILE];

    const int t    = threadIdx.x;
    const int wave = t >> 6;                 // 0..3
    const int lane = t & 63;
    const int tile = blockIdx.x;
    const int img  = tile / TILES_PER_IMG;
    const int tl   = tile % TILES_PER_IMG;
    const int tr   = tl >> 5;                // 32 tile cols per image row
    const int tc   = tl & 31;
    const int origin = img * MULT + (tr * TILE) * W_DIM + tc * TILE;

    // ---- Phase A: load x, build row bitmaps via ballot, identity-init lp ----
    #pragma unroll
    for (int rr = 0; rr < 16; ++rr) {
        int row = wave * 16 + rr;
        float v = x[origin + row * W_DIM + lane];
        unsigned long long m = __ballot(v != 0.0f);
        if (lane == 0) rowmask[row] = m;
    }
    #pragma unroll
    for (int j = 0; j < 4; ++j) {
        int s = t + BLK * j;
        int b = s * 4;
        reinterpret_cast<int4*>(lp)[s] = make_int4(b, b + 1, b + 2, b + 3);
    }
    __syncthreads();

    // ---- Phase B: merges (neighbor tests are register bit-ops on masks) ----
    for (int rr = 0; rr < 16; ++rr) {
        int row = wave * 16 + rr;
        unsigned long long m = rowmask[row];
        if (!((m >> lane) & 1ULL)) continue;       // background pixel
        unsigned long long mu = (row > 0) ? rowmask[row - 1] : 0ULL;
        int p = row * TILE + lane;
        bool lf = (lane > 0)  && ((m  >> (lane - 1)) & 1ULL);
        bool bf =                ((mu >>  lane)      & 1ULL);
        bool af = (lane > 0)  && ((mu >> (lane - 1)) & 1ULL);
        bool cf = (lane < 63) && ((mu >> (lane + 1)) & 1ULL);
        if (lf)                merge_uf(lp, p, p - 1);
        if (bf && !(af && lf)) merge_uf(lp, p, p - TILE);
        if (af && !bf && !lf)  merge_uf(lp, p, p - TILE - 1);
        if (cf && !bf)         merge_uf(lp, p, p - TILE + 1);
    }
    __syncthreads();

    // ---- Phase C: flatten to local root, map to global index, stream out ----
    for (int rr = 0; rr < 16; ++rr) {
        int row = wave * 16 + rr;
        unsigned long long m = rowmask[row];
        int g = -1;
        if ((m >> lane) & 1ULL) {
            int r = find_root(lp, row * TILE + lane);
            g = origin + (r >> 6) * W_DIM + (r & (TILE - 1));
        }
        parent[origin + row * W_DIM + lane] = g;
    }
}

// Phase 2: merge edges that cross tile boundaries (global atomics, rare).
__global__ __launch_bounds__(BLK) void cc_border(int* __restrict__ parent, int total) {
    int tid = blockIdx.x * blockDim.x + threadIdx.x;
    if (tid >= total) return;
    const int per_img = 2 * NB * W_DIM;
    int img = tid / per_img;
    int k   = tid % per_img;
    int base = img * MULT;
    if (k < NB * W_DIM) {
        // horizontal tile boundary: row r (r % 64 == 0), edges to row r-1
        int r = TILE * (1 + k / W_DIM);
        int c = k % W_DIM;
        int i = base + r * W_DIM + c;
        if (parent[i] < 0) return;
        int up = i - W_DIM;
        if (parent[up] >= 0)                      merge_uf(parent, i, up);
        if (c > 0         && parent[up - 1] >= 0) merge_uf(parent, i, up - 1);
        if (c < W_DIM - 1 && parent[up + 1] >= 0) merge_uf(parent, i, up + 1);
    } else {
        // vertical tile boundary: col c (c % 64 == 0), edges to col c-1
        int m = k - NB * W_DIM;
        int c = TILE * (1 + m / H_DIM);
        int r = m % H_DIM;
        int i = base + r * W_DIM + c;
        if (parent[i] < 0) return;
        int lft = i - 1;
        if (parent[lft] >= 0)                            merge_uf(parent, i, lft);
        if (r > 0         && parent[lft - W_DIM] >= 0)   merge_uf(parent, i, lft - W_DIM);
        if (r < H_DIM - 1 && parent[lft + W_DIM] >= 0)   merge_uf(parent, i, lft + W_DIM);
    }
}

// Phase 3 (workspace path): walk to root, write labels. fg flag rides in parent.
__global__ __launch_bounds__(BLK) void cc_write(const int* __restrict__ parent,
                                                float* __restrict__ out, int n4) {
    int i = blockIdx.x * blockDim.x + threadIdx.x;
    if (i >= n4) return;
    int4 p = reinterpret_cast<const int4*>(parent)[i];
    float4 o;
    o.x = (p.x < 0) ? 0.f : (float)(MULT - (find_root(parent, p.x) & (MULT - 1)));
    o.y = (p.y < 0) ? 0.f : (float)(MULT - (find_root(parent, p.y) & (MULT - 1)));
    o.z = (p.z < 0) ? 0.f : (float)(MULT - (find_root(parent, p.z) & (MULT - 1)));
    o.w = (p.w < 0) ? 0.f : (float)(MULT - (find_root(parent, p.w) & (MULT - 1)));
    reinterpret_cast<float4*>(out)[i] = o;
}

// No-workspace path: full path compression, then race-free in-place relabel.
__global__ __launch_bounds__(BLK) void cc_flatten(int* __restrict__ parent, int n) {
    int i = blockIdx.x * blockDim.x + threadIdx.x;
    if (i >= n) return;
    int p = parent[i];
    if (p < 0 || p == i) return;
    int r = find_root(parent, p);
    if (r != p) parent[i] = r;
}

__global__ __launch_bounds__(BLK) void cc_final_inplace(int* __restrict__ parent, int n4) {
    int i = blockIdx.x * blockDim.x + threadIdx.x;
    if (i >= n4) return;
    int4 p = reinterpret_cast<const int4*>(parent)[i];
    float4 o;
    o.x = (p.x < 0) ? 0.f : (float)(MULT - (p.x & (MULT - 1)));
    o.y = (p.y < 0) ? 0.f : (float)(MULT - (p.y & (MULT - 1)));
    o.z = (p.z < 0) ? 0.f : (float)(MULT - (p.z & (MULT - 1)));
    o.w = (p.w < 0) ? 0.f : (float)(MULT - (p.w & (MULT - 1)));
    reinterpret_cast<float4*>(parent)[i] = o;
}

extern "C" void kernel_launch(void* const* d_in, const int* in_sizes, int n_in,
                              void* d_out, int out_size, void* d_ws, size_t ws_size,
                              hipStream_t stream) {
    const float* x = (const float*)d_in[0];
    const int n     = in_sizes[0];          // B*H*W
    const int n_img = n / MULT;
    const int n4    = n / 4;
    const int tiles = n_img * TILES_PER_IMG;
    const int border_threads = n_img * 2 * NB * W_DIM;

    const bool use_ws = (ws_size >= (size_t)n * sizeof(int));
    int* parent = use_ws ? (int*)d_ws : (int*)d_out;

    dim3 blk(BLK);
    cc_local <<<tiles, blk, 0, stream>>>(x, parent);
    cc_border<<<(border_threads + BLK - 1) / BLK, blk, 0, stream>>>(parent, border_threads);
    if (use_ws) {
        cc_write<<<(n4 + BLK - 1) / BLK, blk, 0, stream>>>(parent, (float*)d_out, n4);
    } else {
        cc_flatten      <<<(n + BLK - 1) / BLK, blk, 0, stream>>>(parent, n);
        cc_final_inplace<<<(n4 + BLK - 1) / BLK, blk, 0, stream>>>(parent, n4);
    }
}

// Round 4
// 102.688 us; speedup vs baseline: 1.0001x; 1.0001x over previous
//
#include <hip/hip_runtime.h>

// Two-level connected components: per-tile union-find in LDS driven by
// 64-bit row masks (one wave == one 64-px row, __ballot builds the bitmap),
// then global border merges, then a root-walk relabel.
//
// Label semantics: out = MULT - min(local linear index over 8-conn component)
// for foreground, 0 for background.
//
// parent[] encoding: -1 = background, >=0 = union-find parent (global pixel
// index). parent[p] <= p invariant guarantees termination; every stored value
// is a true ancestor, so stale non-atomic reads remain safe.

constexpr int W_DIM = 2048;
constexpr int H_DIM = 2048;
constexpr int MULT  = W_DIM * H_DIM;        // 2^22 pixels per image
constexpr int TILE  = 64;
constexpr int TPX   = TILE * TILE;          // 4096 pixels per tile
constexpr int BLK   = 256;                  // 4 waves
constexpr int TILES_PER_IMG = MULT / TPX;   // 1024
constexpr int NB    = (H_DIM / TILE) - 1;   // 31 interior boundaries per dim

__device__ __forceinline__ int find_root(const int* p, int v) {
    int q = p[v];
    while (q != v) { v = q; q = p[v]; }
    return v;
}

// atomicMin-based concurrent union; works identically on LDS and global.
__device__ __forceinline__ void merge_uf(int* p, int a, int b) {
    while (true) {
        a = find_root(p, a);
        b = find_root(p, b);
        if (a == b) return;
        if (a < b) { int t = a; a = b; b = t; }  // a > b
        int old = atomicMin(&p[a], b);
        if (old == a) return;                    // a was root; linked under b
        a = old;                                 // displaced; retry from old
    }
}

// Phase 1: per-tile local CCL in LDS; write global parent (bg = -1).
// One wave handles one 64-px row at a time: lane l <-> column l.
__global__ __launch_bounds__(BLK) void cc_local(const float* __restrict__ x,
                                                int* __restrict__ parent) {
    __shared__ int lp[TPX];
    __shared__ unsigned long long rowmask[TILE];

    const int t    = threadIdx.x;
    const int wave = t >> 6;                 // 0..3
    const int lane = t & 63;
    const int tile = blockIdx.x;
    const int img  = tile / TILES_PER_IMG;
    const int tl   = tile % TILES_PER_IMG;
    const int tr   = tl >> 5;                // 32 tile cols per image row
    const int tc   = tl & 31;
    const int origin = img * MULT + (tr * TILE) * W_DIM + tc * TILE;

    // ---- Phase A: load x, build row bitmaps via ballot, identity-init lp ----
    #pragma unroll
    for (int rr = 0; rr < 16; ++rr) {
        int row = wave * 16 + rr;
        float v = x[origin + row * W_DIM + lane];
        unsigned long long m = __ballot(v != 0.0f);
        if (lane == 0) rowmask[row] = m;
    }
    #pragma unroll
    for (int j = 0; j < 4; ++j) {
        int s = t + BLK * j;
        int b = s * 4;
        reinterpret_cast<int4*>(lp)[s] = make_int4(b, b + 1, b + 2, b + 3);
    }
    __syncthreads();

    // ---- Phase B: merges (neighbor tests are register bit-ops on masks) ----
    for (int rr = 0; rr < 16; ++rr) {
        int row = wave * 16 + rr;
        unsigned long long m = rowmask[row];
        if (!((m >> lane) & 1ULL)) continue;       // background pixel
        unsigned long long mu = (row > 0) ? rowmask[row - 1] : 0ULL;
        int p = row * TILE + lane;
        bool lf = (lane > 0)  && ((m  >> (lane - 1)) & 1ULL);
        bool bf =                ((mu >>  lane)      & 1ULL);
        bool af = (lane > 0)  && ((mu >> (lane - 1)) & 1ULL);
        bool cf = (lane < 63) && ((mu >> (lane + 1)) & 1ULL);
        if (lf)                merge_uf(lp, p, p - 1);
        if (bf && !(af && lf)) merge_uf(lp, p, p - TILE);
        if (af && !bf && !lf)  merge_uf(lp, p, p - TILE - 1);
        if (cf && !bf)         merge_uf(lp, p, p - TILE + 1);
    }
    __syncthreads();

    // ---- Phase C: flatten to local root, map to global index, stream out ----
    for (int rr = 0; rr < 16; ++rr) {
        int row = wave * 16 + rr;
        unsigned long long m = rowmask[row];
        int g = -1;
        if ((m >> lane) & 1ULL) {
            int r = find_root(lp, row * TILE + lane);
            g = origin + (r >> 6) * W_DIM + (r & (TILE - 1));
        }
        parent[origin + row * W_DIM + lane] = g;
    }
}

// Phase 2: merge edges that cross tile boundaries (global atomics, rare).
__global__ __launch_bounds__(BLK) void cc_border(int* __restrict__ parent, int total) {
    int tid = blockIdx.x * blockDim.x + threadIdx.x;
    if (tid >= total) return;
    const int per_img = 2 * NB * W_DIM;
    int img = tid / per_img;
    int k   = tid % per_img;
    int base = img * MULT;
    if (k < NB * W_DIM) {
        // horizontal tile boundary: row r (r % 64 == 0), edges to row r-1
        int r = TILE * (1 + k / W_DIM);
        int c = k % W_DIM;
        int i = base + r * W_DIM + c;
        if (parent[i] < 0) return;
        int up = i - W_DIM;
        if (parent[up] >= 0)                      merge_uf(parent, i, up);
        if (c > 0         && parent[up - 1] >= 0) merge_uf(parent, i, up - 1);
        if (c < W_DIM - 1 && parent[up + 1] >= 0) merge_uf(parent, i, up + 1);
    } else {
        // vertical tile boundary: col c (c % 64 == 0), edges to col c-1
        int m = k - NB * W_DIM;
        int c = TILE * (1 + m / H_DIM);
        int r = m % H_DIM;
        int i = base + r * W_DIM + c;
        if (parent[i] < 0) return;
        int lft = i - 1;
        if (parent[lft] >= 0)                            merge_uf(parent, i, lft);
        if (r > 0         && parent[lft - W_DIM] >= 0)   merge_uf(parent, i, lft - W_DIM);
        if (r < H_DIM - 1 && parent[lft + W_DIM] >= 0)   merge_uf(parent, i, lft + W_DIM);
    }
}

// Phase 3 (workspace path): walk to root, write labels. fg flag rides in parent.
__global__ __launch_bounds__(BLK) void cc_write(const int* __restrict__ parent,
                                                float* __restrict__ out, int n4) {
    int i = blockIdx.x * blockDim.x + threadIdx.x;
    if (i >= n4) return;
    int4 p = reinterpret_cast<const int4*>(parent)[i];
    float4 o;
    o.x = (p.x < 0) ? 0.f : (float)(MULT - (find_root(parent, p.x) & (MULT - 1)));
    o.y = (p.y < 0) ? 0.f : (float)(MULT - (find_root(parent, p.y) & (MULT - 1)));
    o.z = (p.z < 0) ? 0.f : (float)(MULT - (find_root(parent, p.z) & (MULT - 1)));
    o.w = (p.w < 0) ? 0.f : (float)(MULT - (find_root(parent, p.w) & (MULT - 1)));
    reinterpret_cast<float4*>(out)[i] = o;
}

// No-workspace path: full path compression, then race-free in-place relabel.
__global__ __launch_bounds__(BLK) void cc_flatten(int* __restrict__ parent, int n) {
    int i = blockIdx.x * blockDim.x + threadIdx.x;
    if (i >= n) return;
    int p = parent[i];
    if (p < 0 || p == i) return;
    int r = find_root(parent, p);
    if (r != p) parent[i] = r;
}

__global__ __launch_bounds__(BLK) void cc_final_inplace(int* __restrict__ parent, int n4) {
    int i = blockIdx.x * blockDim.x + threadIdx.x;
    if (i >= n4) return;
    int4 p = reinterpret_cast<const int4*>(parent)[i];
    float4 o;
    o.x = (p.x < 0) ? 0.f : (float)(MULT - (p.x & (MULT - 1)));
    o.y = (p.y < 0) ? 0.f : (float)(MULT - (p.y & (MULT - 1)));
    o.z = (p.z < 0) ? 0.f : (float)(MULT - (p.z & (MULT - 1)));
    o.w = (p.w < 0) ? 0.f : (float)(MULT - (p.w & (MULT - 1)));
    reinterpret_cast<float4*>(parent)[i] = o;
}

extern "C" void kernel_launch(void* const* d_in, const int* in_sizes, int n_in,
                              void* d_out, int out_size, void* d_ws, size_t ws_size,
                              hipStream_t stream) {
    const float* x = (const float*)d_in[0];
    const int n     = in_sizes[0];          // B*H*W
    const int n_img = n / MULT;
    const int n4    = n / 4;
    const int tiles = n_img * TILES_PER_IMG;
    const int border_threads = n_img * 2 * NB * W_DIM;

    const bool use_ws = (ws_size >= (size_t)n * sizeof(int));
    int* parent = use_ws ? (int*)d_ws : (int*)d_out;

    dim3 blk(BLK);
    cc_local <<<tiles, blk, 0, stream>>>(x, parent);
    cc_border<<<(border_threads + BLK - 1) / BLK, blk, 0, stream>>>(parent, border_threads);
    if (use_ws) {
        cc_write<<<(n4 + BLK - 1) / BLK, blk, 0, stream>>>(parent, (float*)d_out, n4);
    } else {
        cc_flatten      <<<(n + BLK - 1) / BLK, blk, 0, stream>>>(parent, n);
        cc_final_inplace<<<(n4 + BLK - 1) / BLK, blk, 0, stream>>>(parent, n4);
    }
}

// Round 5
// 90.152 us; speedup vs baseline: 1.1391x; 1.1391x over previous
//
#include <hip/hip_runtime.h>

// Two-level connected components. Local phase: per-tile union-find in LDS,
// driven by wave-uniform 64-bit row masks (__ballot -> SGPR); all per-row
// merge-candidate sets are computed with SCALAR 64-bit mask algebra, so the
// per-lane cost is 4 predicated bit tests + rarely-taken merges. Then global
// border merges, then a root-walk relabel with explicit load-ILP.
//
// Label semantics: out = MULT - min(local linear index over 8-conn component)
// for foreground, 0 for background.
//
// parent[] encoding: -1 = background, >=0 = union-find parent (global pixel
// index). parent[p] <= p invariant guarantees termination; every stored value
// is a true ancestor, so stale non-atomic reads remain safe.

constexpr int W_DIM = 2048;
constexpr int H_DIM = 2048;
constexpr int MULT  = W_DIM * H_DIM;        // 2^22 pixels per image
constexpr int TILE  = 64;
constexpr int TPX   = TILE * TILE;          // 4096 pixels per tile
constexpr int BLK   = 256;                  // 4 waves
constexpr int TILES_PER_IMG = MULT / TPX;   // 1024
constexpr int NB    = (H_DIM / TILE) - 1;   // 31 interior boundaries per dim

__device__ __forceinline__ int find_root(const int* p, int v) {
    int q = p[v];
    while (q != v) { v = q; q = p[v]; }
    return v;
}

// atomicMin-based concurrent union; works identically on LDS and global.
__device__ __forceinline__ void merge_uf(int* p, int a, int b) {
    while (true) {
        a = find_root(p, a);
        b = find_root(p, b);
        if (a == b) return;
        if (a < b) { int t = a; a = b; b = t; }  // a > b
        int old = atomicMin(&p[a], b);
        if (old == a) return;                    // a was root; linked under b
        a = old;                                 // displaced; retry from old
    }
}

// Phase 1: per-tile local CCL in LDS; write global parent (bg = -1).
// One wave owns 16 consecutive 64-px rows; lane l <-> column l.
__global__ __launch_bounds__(BLK) void cc_local(const float* __restrict__ x,
                                                int* __restrict__ parent) {
    __shared__ int lp[TPX];
    __shared__ unsigned long long bmask[4];  // each wave's last-row mask

    const int t    = threadIdx.x;
    const int wave = t >> 6;                 // 0..3
    const int lane = t & 63;
    const int tile = blockIdx.x;
    const int img  = tile / TILES_PER_IMG;
    const int tl   = tile % TILES_PER_IMG;
    const int tr   = tl >> 5;                // 32 tile cols per image row
    const int tc   = tl & 31;
    const int origin = img * MULT + (tr * TILE) * W_DIM + tc * TILE;

    // ---- Phase A: load x, build wave-resident row bitmaps, identity-init lp
    unsigned long long m[16];
    #pragma unroll
    for (int rr = 0; rr < 16; ++rr) {
        int row = wave * 16 + rr;
        float v = x[origin + row * W_DIM + lane];
        m[rr] = __ballot(v != 0.0f);
    }
    if (lane == 0) bmask[wave] = m[15];
    #pragma unroll
    for (int j = 0; j < 4; ++j) {
        int s = t + BLK * j;
        int b = s * 4;
        reinterpret_cast<int4*>(lp)[s] = make_int4(b, b + 1, b + 2, b + 3);
    }
    __syncthreads();

    const unsigned long long mu0 = (wave > 0) ? bmask[wave - 1] : 0ULL;

    // ---- Phase B: merges. Candidate sets are scalar mask algebra:
    //   lmask : fg & left-fg                          -> merge (p, p-1)
    //   bfmask: fg & up-fg & !(upleft-fg & left-fg)   -> merge (p, p-64)
    //   afmask: fg & upleft-fg & !up-fg & !left-fg    -> merge (p, p-65)
    //   cfmask: fg & upright-fg & !up-fg              -> merge (p, p-63)
    // (identical to the verified round-3 boolean suppression logic)
    #pragma unroll
    for (int rr = 0; rr < 16; ++rr) {
        const unsigned long long mm = m[rr];
        if (mm == 0ULL) continue;                       // wave-uniform skip
        const unsigned long long mu = (rr == 0) ? mu0 : m[rr - 1];
        const int p = (wave * 16 + rr) * TILE + lane;
        const unsigned long long lmask  = mm & (mm << 1);
        const unsigned long long bfmask = mm & mu & ~((mm << 1) & (mu << 1));
        const unsigned long long afmask = mm & (mu << 1) & ~mu & ~(mm << 1);
        const unsigned long long cfmask = mm & (mu >> 1) & ~mu;
        if ((lmask  >> lane) & 1ULL) merge_uf(lp, p, p - 1);
        if ((bfmask >> lane) & 1ULL) merge_uf(lp, p, p - TILE);
        if ((afmask >> lane) & 1ULL) merge_uf(lp, p, p - TILE - 1);
        if ((cfmask >> lane) & 1ULL) merge_uf(lp, p, p - TILE + 1);
    }
    __syncthreads();

    // ---- Phase C: prefetch all first-hop reads (ILP), walk only if needed,
    // map local root -> global index, stream out.
    int q[16];
    #pragma unroll
    for (int rr = 0; rr < 16; ++rr)
        q[rr] = lp[(wave * 16 + rr) * TILE + lane];     // stride-1: conflict-free

    #pragma unroll
    for (int rr = 0; rr < 16; ++rr) {
        int row = wave * 16 + rr;
        int p   = row * TILE + lane;
        int g   = -1;
        if ((m[rr] >> lane) & 1ULL) {
            int v = q[rr];
            if (v != p) {                                // rare: walk the chain
                int w = lp[v];
                while (w != v) { v = w; w = lp[v]; }
            }
            g = origin + (v >> 6) * W_DIM + (v & (TILE - 1));
        }
        parent[origin + row * W_DIM + lane] = g;
    }
}

// Phase 2: merge edges that cross tile boundaries (global atomics, rare).
__global__ __launch_bounds__(BLK) void cc_border(int* __restrict__ parent, int total) {
    int tid = blockIdx.x * blockDim.x + threadIdx.x;
    if (tid >= total) return;
    const int per_img = 2 * NB * W_DIM;
    int img = tid / per_img;
    int k   = tid % per_img;
    int base = img * MULT;
    if (k < NB * W_DIM) {
        // horizontal tile boundary: row r (r % 64 == 0), edges to row r-1
        int r = TILE * (1 + k / W_DIM);
        int c = k % W_DIM;
        int i = base + r * W_DIM + c;
        if (parent[i] < 0) return;
        int up = i - W_DIM;
        if (parent[up] >= 0)                      merge_uf(parent, i, up);
        if (c > 0         && parent[up - 1] >= 0) merge_uf(parent, i, up - 1);
        if (c < W_DIM - 1 && parent[up + 1] >= 0) merge_uf(parent, i, up + 1);
    } else {
        // vertical tile boundary: col c (c % 64 == 0), edges to col c-1
        int m = k - NB * W_DIM;
        int c = TILE * (1 + m / H_DIM);
        int r = m % H_DIM;
        int i = base + r * W_DIM + c;
        if (parent[i] < 0) return;
        int lft = i - 1;
        if (parent[lft] >= 0)                            merge_uf(parent, i, lft);
        if (r > 0         && parent[lft - W_DIM] >= 0)   merge_uf(parent, i, lft - W_DIM);
        if (r < H_DIM - 1 && parent[lft + W_DIM] >= 0)   merge_uf(parent, i, lft + W_DIM);
    }
}

// Phase 3 (workspace path): walk to root, write labels. fg flag rides in
// parent. Issue all 4 first-hop loads before any walk (load ILP).
__global__ __launch_bounds__(BLK) void cc_write(const int* __restrict__ parent,
                                                float* __restrict__ out, int n4) {
    int i = blockIdx.x * blockDim.x + threadIdx.x;
    if (i >= n4) return;
    int4 p = reinterpret_cast<const int4*>(parent)[i];
    int a0 = (p.x >= 0) ? parent[p.x] : 0;
    int a1 = (p.y >= 0) ? parent[p.y] : 0;
    int a2 = (p.z >= 0) ? parent[p.z] : 0;
    int a3 = (p.w >= 0) ? parent[p.w] : 0;
    float4 o;
    {
        int v = p.x, w = a0;
        if (v >= 0) { while (w != v) { v = w; w = parent[v]; } }
        o.x = (p.x < 0) ? 0.f : (float)(MULT - (v & (MULT - 1)));
    }
    {
        int v = p.y, w = a1;
        if (v >= 0) { while (w != v) { v = w; w = parent[v]; } }
        o.y = (p.y < 0) ? 0.f : (float)(MULT - (v & (MULT - 1)));
    }
    {
        int v = p.z, w = a2;
        if (v >= 0) { while (w != v) { v = w; w = parent[v]; } }
        o.z = (p.z < 0) ? 0.f : (float)(MULT - (v & (MULT - 1)));
    }
    {
        int v = p.w, w = a3;
        if (v >= 0) { while (w != v) { v = w; w = parent[v]; } }
        o.w = (p.w < 0) ? 0.f : (float)(MULT - (v & (MULT - 1)));
    }
    reinterpret_cast<float4*>(out)[i] = o;
}

// No-workspace path: full path compression, then race-free in-place relabel.
__global__ __launch_bounds__(BLK) void cc_flatten(int* __restrict__ parent, int n) {
    int i = blockIdx.x * blockDim.x + threadIdx.x;
    if (i >= n) return;
    int p = parent[i];
    if (p < 0 || p == i) return;
    int r = find_root(parent, p);
    if (r != p) parent[i] = r;
}

__global__ __launch_bounds__(BLK) void cc_final_inplace(int* __restrict__ parent, int n4) {
    int i = blockIdx.x * blockDim.x + threadIdx.x;
    if (i >= n4) return;
    int4 p = reinterpret_cast<const int4*>(parent)[i];
    float4 o;
    o.x = (p.x < 0) ? 0.f : (float)(MULT - (p.x & (MULT - 1)));
    o.y = (p.y < 0) ? 0.f : (float)(MULT - (p.y & (MULT - 1)));
    o.z = (p.z < 0) ? 0.f : (float)(MULT - (p.z & (MULT - 1)));
    o.w = (p.w < 0) ? 0.f : (float)(MULT - (p.w & (MULT - 1)));
    reinterpret_cast<float4*>(parent)[i] = o;
}

extern "C" void kernel_launch(void* const* d_in, const int* in_sizes, int n_in,
                              void* d_out, int out_size, void* d_ws, size_t ws_size,
                              hipStream_t stream) {
    const float* x = (const float*)d_in[0];
    const int n     = in_sizes[0];          // B*H*W
    const int n_img = n / MULT;
    const int n4    = n / 4;
    const int tiles = n_img * TILES_PER_IMG;
    const int border_threads = n_img * 2 * NB * W_DIM;

    const bool use_ws = (ws_size >= (size_t)n * sizeof(int));
    int* parent = use_ws ? (int*)d_ws : (int*)d_out;

    dim3 blk(BLK);
    cc_local <<<tiles, blk, 0, stream>>>(x, parent);
    cc_border<<<(border_threads + BLK - 1) / BLK, blk, 0, stream>>>(parent, border_threads);
    if (use_ws) {
        cc_write<<<(n4 + BLK - 1) / BLK, blk, 0, stream>>>(parent, (float*)d_out, n4);
    } else {
        cc_flatten      <<<(n + BLK - 1) / BLK, blk, 0, stream>>>(parent, n);
        cc_final_inplace<<<(n4 + BLK - 1) / BLK, blk, 0, stream>>>(parent, n4);
    }
}

// Round 6
// 71.819 us; speedup vs baseline: 1.4299x; 1.2553x over previous
//
#include <hip/hip_runtime.h>

// Two-level connected components. Local phase: per-tile union-find in LDS.
// Row foreground bitmaps live in SGPRs (__ballot); merge-candidate sets are
// scalar 64-bit mask algebra; each lane's pending merges are packed into ONE
// 64-bit register bitset and drained in a batched loop so the whole wave pays
// the LDS find_root latency ~max-popcount times (~3-4) instead of once per
// merge site (~30). Then global border merges, then root-walk relabel.
//
// Label semantics: out = MULT - min(local linear index over 8-conn component)
// for foreground, 0 for background.
//
// parent[] encoding: -1 = background, >=0 = union-find parent (global pixel
// index). parent[p] <= p invariant guarantees termination; every stored value
// is a true ancestor, so stale non-atomic reads remain safe.

constexpr int W_DIM = 2048;
constexpr int H_DIM = 2048;
constexpr int MULT  = W_DIM * H_DIM;        // 2^22 pixels per image
constexpr int TILE  = 64;
constexpr int TPX   = TILE * TILE;          // 4096 pixels per tile
constexpr int BLK   = 256;                  // 4 waves
constexpr int TILES_PER_IMG = MULT / TPX;   // 1024
constexpr int NB    = (H_DIM / TILE) - 1;   // 31 interior boundaries per dim

__device__ __forceinline__ int find_root(const int* p, int v) {
    int q = p[v];
    while (q != v) { v = q; q = p[v]; }
    return v;
}

// atomicMin-based concurrent union; works identically on LDS and global.
__device__ __forceinline__ void merge_uf(int* p, int a, int b) {
    while (true) {
        a = find_root(p, a);
        b = find_root(p, b);
        if (a == b) return;
        if (a < b) { int t = a; a = b; b = t; }  // a > b
        int old = atomicMin(&p[a], b);
        if (old == a) return;                    // a was root; linked under b
        a = old;                                 // displaced; retry from old
    }
}

// Phase 1: per-tile local CCL in LDS; write global parent (bg = -1).
// One wave owns 16 consecutive 64-px rows; lane l <-> column l.
__global__ __launch_bounds__(BLK) void cc_local(const float* __restrict__ x,
                                                int* __restrict__ parent) {
    __shared__ int lp[TPX];
    __shared__ unsigned long long rowmask_sh[TILE];

    const int t    = threadIdx.x;
    const int wave = t >> 6;                 // 0..3
    const int lane = t & 63;
    const int tile = blockIdx.x;
    const int img  = tile / TILES_PER_IMG;
    const int tl   = tile % TILES_PER_IMG;
    const int tr   = tl >> 5;                // 32 tile cols per image row
    const int tc   = tl & 31;
    const int origin = img * MULT + (tr * TILE) * W_DIM + tc * TILE;

    // ---- Phase A: load x, build row bitmaps (SGPR + LDS copy), init lp ----
    unsigned long long m[16];
    #pragma unroll
    for (int rr = 0; rr < 16; ++rr) {
        int row = wave * 16 + rr;
        float v = x[origin + row * W_DIM + lane];
        m[rr] = __ballot(v != 0.0f);
    }
    if (lane == 0) {
        #pragma unroll
        for (int rr = 0; rr < 16; ++rr) rowmask_sh[wave * 16 + rr] = m[rr];
    }
    #pragma unroll
    for (int j = 0; j < 4; ++j) {
        int s = t + BLK * j;
        int b = s * 4;
        reinterpret_cast<int4*>(lp)[s] = make_int4(b, b + 1, b + 2, b + 3);
    }
    __syncthreads();

    const unsigned long long mu0 = (wave > 0) ? rowmask_sh[wave * 16 - 1] : 0ULL;

    // ---- Phase B1: build per-lane merge bitset (bit 4*rr+type) ----
    //   type 0: left (-1)      lmask  = mm & (mm<<1)
    //   type 1: up (-64)       bfmask = mm & mu & ~((mm<<1)&(mu<<1))
    //   type 2: up-left (-65)  afmask = mm & (mu<<1) & ~mu & ~(mm<<1)
    //   type 3: up-right(-63)  cfmask = mm & (mu>>1) & ~mu
    // (identical edge set to the verified round-3/5 suppression logic)
    unsigned long long bits = 0ULL;
    #pragma unroll
    for (int rr = 0; rr < 16; ++rr) {
        const unsigned long long mm = m[rr];
        const unsigned long long mu = (rr == 0) ? mu0 : m[rr - 1];
        const unsigned long long lmask  = mm & (mm << 1);
        const unsigned long long bfmask = mm & mu & ~((mm << 1) & (mu << 1));
        const unsigned long long afmask = mm & (mu << 1) & ~mu & ~(mm << 1);
        const unsigned long long cfmask = mm & (mu >> 1) & ~mu;
        unsigned nib = (unsigned)((lmask  >> lane) & 1ULL)
                     | ((unsigned)((bfmask >> lane) & 1ULL) << 1)
                     | ((unsigned)((afmask >> lane) & 1ULL) << 2)
                     | ((unsigned)((cfmask >> lane) & 1ULL) << 3);
        bits |= (unsigned long long)nib << (rr * 4);
    }

    // ---- Phase B2: drain merges batched — all lanes merge concurrently ----
    while (__any(bits != 0ULL)) {
        if (bits) {
            int idx = (int)__builtin_ctzll(bits);
            bits &= bits - 1;
            int rr = idx >> 2, ty = idx & 3;
            int p  = (wave * 16 + rr) * TILE + lane;
            int off = (ty & 2) ? ((ty & 1) ? -(TILE - 1) : -(TILE + 1))
                               : ((ty & 1) ? -TILE : -1);
            merge_uf(lp, p, p + off);
        }
    }
    __syncthreads();

    // ---- Phase C: b128 reads of lp, resolve roots, int4 stores of parent ----
    #pragma unroll
    for (int j = 0; j < 4; ++j) {
        int s   = t + BLK * j;               // int4 slot in tile
        int row = s >> 4;                    // 16 slots per 64-px row
        int c4  = s & 15;
        int p0  = row * TILE + c4 * 4;
        int4 q  = reinterpret_cast<const int4*>(lp)[s];
        unsigned fgbits = (unsigned)((rowmask_sh[row] >> (c4 * 4)) & 0xFULL);
        int4 o;
        {
            int g = -1;
            if (fgbits & 1u) {
                int v = q.x, p = p0;
                if (v != p) { int w = lp[v]; while (w != v) { v = w; w = lp[v]; } }
                g = origin + (v >> 6) * W_DIM + (v & (TILE - 1));
            }
            o.x = g;
        }
        {
            int g = -1;
            if (fgbits & 2u) {
                int v = q.y, p = p0 + 1;
                if (v != p) { int w = lp[v]; while (w != v) { v = w; w = lp[v]; } }
                g = origin + (v >> 6) * W_DIM + (v & (TILE - 1));
            }
            o.y = g;
        }
        {
            int g = -1;
            if (fgbits & 4u) {
                int v = q.z, p = p0 + 2;
                if (v != p) { int w = lp[v]; while (w != v) { v = w; w = lp[v]; } }
                g = origin + (v >> 6) * W_DIM + (v & (TILE - 1));
            }
            o.z = g;
        }
        {
            int g = -1;
            if (fgbits & 8u) {
                int v = q.w, p = p0 + 3;
                if (v != p) { int w = lp[v]; while (w != v) { v = w; w = lp[v]; } }
                g = origin + (v >> 6) * W_DIM + (v & (TILE - 1));
            }
            o.w = g;
        }
        reinterpret_cast<int4*>(parent + origin + row * W_DIM)[c4] = o;
    }
}

// Phase 2: merge edges that cross tile boundaries (global atomics, rare).
__global__ __launch_bounds__(BLK) void cc_border(int* __restrict__ parent, int total) {
    int tid = blockIdx.x * blockDim.x + threadIdx.x;
    if (tid >= total) return;
    const int per_img = 2 * NB * W_DIM;
    int img = tid / per_img;
    int k   = tid % per_img;
    int base = img * MULT;
    if (k < NB * W_DIM) {
        // horizontal tile boundary: row r (r % 64 == 0), edges to row r-1
        int r = TILE * (1 + k / W_DIM);
        int c = k % W_DIM;
        int i = base + r * W_DIM + c;
        if (parent[i] < 0) return;
        int up = i - W_DIM;
        if (parent[up] >= 0)                      merge_uf(parent, i, up);
        if (c > 0         && parent[up - 1] >= 0) merge_uf(parent, i, up - 1);
        if (c < W_DIM - 1 && parent[up + 1] >= 0) merge_uf(parent, i, up + 1);
    } else {
        // vertical tile boundary: col c (c % 64 == 0), edges to col c-1
        int m = k - NB * W_DIM;
        int c = TILE * (1 + m / H_DIM);
        int r = m % H_DIM;
        int i = base + r * W_DIM + c;
        if (parent[i] < 0) return;
        int lft = i - 1;
        if (parent[lft] >= 0)                            merge_uf(parent, i, lft);
        if (r > 0         && parent[lft - W_DIM] >= 0)   merge_uf(parent, i, lft - W_DIM);
        if (r < H_DIM - 1 && parent[lft + W_DIM] >= 0)   merge_uf(parent, i, lft + W_DIM);
    }
}

// Phase 3 (workspace path): walk to root, write labels. fg flag rides in
// parent. Issue all 4 first-hop loads before any walk (load ILP).
__global__ __launch_bounds__(BLK) void cc_write(const int* __restrict__ parent,
                                                float* __restrict__ out, int n4) {
    int i = blockIdx.x * blockDim.x + threadIdx.x;
    if (i >= n4) return;
    int4 p = reinterpret_cast<const int4*>(parent)[i];
    int a0 = (p.x >= 0) ? parent[p.x] : 0;
    int a1 = (p.y >= 0) ? parent[p.y] : 0;
    int a2 = (p.z >= 0) ? parent[p.z] : 0;
    int a3 = (p.w >= 0) ? parent[p.w] : 0;
    float4 o;
    {
        int v = p.x, w = a0;
        if (v >= 0) { while (w != v) { v = w; w = parent[v]; } }
        o.x = (p.x < 0) ? 0.f : (float)(MULT - (v & (MULT - 1)));
    }
    {
        int v = p.y, w = a1;
        if (v >= 0) { while (w != v) { v = w; w = parent[v]; } }
        o.y = (p.y < 0) ? 0.f : (float)(MULT - (v & (MULT - 1)));
    }
    {
        int v = p.z, w = a2;
        if (v >= 0) { while (w != v) { v = w; w = parent[v]; } }
        o.z = (p.z < 0) ? 0.f : (float)(MULT - (v & (MULT - 1)));
    }
    {
        int v = p.w, w = a3;
        if (v >= 0) { while (w != v) { v = w; w = parent[v]; } }
        o.w = (p.w < 0) ? 0.f : (float)(MULT - (v & (MULT - 1)));
    }
    reinterpret_cast<float4*>(out)[i] = o;
}

// No-workspace path: full path compression, then race-free in-place relabel.
__global__ __launch_bounds__(BLK) void cc_flatten(int* __restrict__ parent, int n) {
    int i = blockIdx.x * blockDim.x + threadIdx.x;
    if (i >= n) return;
    int p = parent[i];
    if (p < 0 || p == i) return;
    int r = find_root(parent, p);
    if (r != p) parent[i] = r;
}

__global__ __launch_bounds__(BLK) void cc_final_inplace(int* __restrict__ parent, int n4) {
    int i = blockIdx.x * blockDim.x + threadIdx.x;
    if (i >= n4) return;
    int4 p = reinterpret_cast<const int4*>(parent)[i];
    float4 o;
    o.x = (p.x < 0) ? 0.f : (float)(MULT - (p.x & (MULT - 1)));
    o.y = (p.y < 0) ? 0.f : (float)(MULT - (p.y & (MULT - 1)));
    o.z = (p.z < 0) ? 0.f : (float)(MULT - (p.z & (MULT - 1)));
    o.w = (p.w < 0) ? 0.f : (float)(MULT - (p.w & (MULT - 1)));
    reinterpret_cast<float4*>(parent)[i] = o;
}

extern "C" void kernel_launch(void* const* d_in, const int* in_sizes, int n_in,
                              void* d_out, int out_size, void* d_ws, size_t ws_size,
                              hipStream_t stream) {
    const float* x = (const float*)d_in[0];
    const int n     = in_sizes[0];          // B*H*W
    const int n_img = n / MULT;
    const int n4    = n / 4;
    const int tiles = n_img * TILES_PER_IMG;
    const int border_threads = n_img * 2 * NB * W_DIM;

    const bool use_ws = (ws_size >= (size_t)n * sizeof(int));
    int* parent = use_ws ? (int*)d_ws : (int*)d_out;

    dim3 blk(BLK);
    cc_local <<<tiles, blk, 0, stream>>>(x, parent);
    cc_border<<<(border_threads + BLK - 1) / BLK, blk, 0, stream>>>(parent, border_threads);
    if (use_ws) {
        cc_write<<<(n4 + BLK - 1) / BLK, blk, 0, stream>>>(parent, (float*)d_out, n4);
    } else {
        cc_flatten      <<<(n + BLK - 1) / BLK, blk, 0, stream>>>(parent, n);
        cc_final_inplace<<<(n4 + BLK - 1) / BLK, blk, 0, stream>>>(parent, n4);
    }
}

// Round 7
// 68.192 us; speedup vs baseline: 1.5060x; 1.0532x over previous
//
#include <hip/hip_runtime.h>

// Two-level connected components, fused output:
//  - cc_local: per-tile union-find in LDS (ballot row masks, scalar mask
//    algebra, batched merge drain). Writes FINAL labels to out directly;
//    components touching the tile strip are marked via an LDS root-bitset,
//    their pixels appended to a per-tile worklist slab, their strip pixels
//    and roots seed a SPARSE global parent array, and per-row fg masks go
//    to a 2MB bitmap.
//  - cc_border_bm: cross-tile merges; fg tests from the bitmap, union-find
//    on the sparse parent (all endpoints are initialized strip pixels).
//  - cc_fixup: walks worklist entries only (~1.5% of pixels), overwrites
//    their labels with the post-merge root.
//
// Label semantics: out = MULT - min(local linear index over 8-conn component)
// for foreground, 0 for background.
//
// UF invariant: parent[v] <= v, every stored value is a true ancestor ->
// atomicMin linking converges to exact min-index roots (verified r1-r6).

constexpr int W_DIM = 2048;
constexpr int H_DIM = 2048;
constexpr int MULT  = W_DIM * H_DIM;        // 2^22 pixels per image
constexpr int TILE  = 64;
constexpr int TPX   = TILE * TILE;          // 4096 pixels per tile
constexpr int BLK   = 256;                  // 4 waves
constexpr int TILES_PER_IMG = MULT / TPX;   // 1024
constexpr int NB    = (H_DIM / TILE) - 1;   // 31 interior boundaries per dim
constexpr int WCAP  = 512;                  // per-tile worklist capacity
constexpr int OVF_CAP = 65536;              // global overflow capacity

__device__ __forceinline__ int find_root(const int* p, int v) {
    int q = p[v];
    while (q != v) { v = q; q = p[v]; }
    return v;
}

__device__ __forceinline__ void merge_uf(int* p, int a, int b) {
    while (true) {
        a = find_root(p, a);
        b = find_root(p, b);
        if (a == b) return;
        if (a < b) { int t = a; a = b; b = t; }  // a > b
        int old = atomicMin(&p[a], b);
        if (old == a) return;                    // a was root; linked under b
        a = old;                                 // displaced; retry from old
    }
}

// MODE 0: legacy (write full parent). MODE 1: fused (write out + sparse UF).
template <int MODE>
__global__ __launch_bounds__(BLK) void cc_local(const float* __restrict__ x,
                                                int* __restrict__ parent,
                                                float* __restrict__ out,
                                                unsigned long long* __restrict__ bitmap,
                                                int2* __restrict__ slabs,
                                                int* __restrict__ wl_cnt,
                                                int2* __restrict__ ovf,
                                                int* __restrict__ ovf_cnt) {
    __shared__ int lp[TPX];
    __shared__ unsigned long long rowmask_sh[TILE];
    __shared__ unsigned int bc[TPX / 32];    // border-component root bitset
    __shared__ int cursor;

    const int t    = threadIdx.x;
    const int wave = t >> 6;                 // 0..3
    const int lane = t & 63;
    const int tile = blockIdx.x;
    const int img  = tile / TILES_PER_IMG;
    const int tl   = tile % TILES_PER_IMG;
    const int tr   = tl >> 5;                // 32 tile cols per image row
    const int tc   = tl & 31;
    const int origin = img * MULT + (tr * TILE) * W_DIM + tc * TILE;

    // ---- Phase A: load x, ballot row bitmaps, init lp / bc / cursor ----
    unsigned long long m[16];
    #pragma unroll
    for (int rr = 0; rr < 16; ++rr) {
        int row = wave * 16 + rr;
        float v = x[origin + row * W_DIM + lane];
        m[rr] = __ballot(v != 0.0f);
    }
    if (lane == 0) {
        #pragma unroll
        for (int rr = 0; rr < 16; ++rr) {
            rowmask_sh[wave * 16 + rr] = m[rr];
            if constexpr (MODE == 1) {
                int grow = tr * TILE + wave * 16 + rr;
                bitmap[(img * H_DIM + grow) * (W_DIM / 64) + tc] = m[rr];
            }
        }
    }
    if constexpr (MODE == 1) {
        if (t < TPX / 32) bc[t] = 0u;
        if (t == 0) cursor = 0;
    }
    #pragma unroll
    for (int j = 0; j < 4; ++j) {
        int s = t + BLK * j;
        int b = s * 4;
        reinterpret_cast<int4*>(lp)[s] = make_int4(b, b + 1, b + 2, b + 3);
    }
    __syncthreads();

    const unsigned long long mu0 = (wave > 0) ? rowmask_sh[wave * 16 - 1] : 0ULL;

    // ---- Phase B1: per-lane merge bitset (bit 4*rr+type) ----
    unsigned long long bits = 0ULL;
    #pragma unroll
    for (int rr = 0; rr < 16; ++rr) {
        const unsigned long long mm = m[rr];
        const unsigned long long mu = (rr == 0) ? mu0 : m[rr - 1];
        const unsigned long long lmask  = mm & (mm << 1);
        const unsigned long long bfmask = mm & mu & ~((mm << 1) & (mu << 1));
        const unsigned long long afmask = mm & (mu << 1) & ~mu & ~(mm << 1);
        const unsigned long long cfmask = mm & (mu >> 1) & ~mu;
        unsigned nib = (unsigned)((lmask  >> lane) & 1ULL)
                     | ((unsigned)((bfmask >> lane) & 1ULL) << 1)
                     | ((unsigned)((afmask >> lane) & 1ULL) << 2)
                     | ((unsigned)((cfmask >> lane) & 1ULL) << 3);
        bits |= (unsigned long long)nib << (rr * 4);
    }

    // ---- Phase B2: batched merge drain ----
    while (__any(bits != 0ULL)) {
        if (bits) {
            int idx = (int)__builtin_ctzll(bits);
            bits &= bits - 1;
            int rr = idx >> 2, ty = idx & 3;
            int p  = (wave * 16 + rr) * TILE + lane;
            int off = (ty & 2) ? ((ty & 1) ? -(TILE - 1) : -(TILE + 1))
                               : ((ty & 1) ? -TILE : -1);
            merge_uf(lp, p, p + off);
        }
    }
    __syncthreads();

    // ---- Marking pass (MODE 1): strip fg pixels mark their root as a
    // border component and seed the sparse global parent. ----
    if constexpr (MODE == 1) {
        const bool has_up = tr > 0, has_dn = tr < 31;
        const bool has_lf = tc > 0, has_rt = tc < 31;
        #pragma unroll
        for (int rr = 0; rr < 16; ++rr) {
            int row = wave * 16 + rr;
            bool fg = (m[rr] >> lane) & 1ULL;
            bool strip = (row == 0 && has_up) || (row == TILE - 1 && has_dn) ||
                         (lane == 0 && has_lf) || (lane == TILE - 1 && has_rt);
            if (fg && strip) {
                int p = row * TILE + lane;
                int v = find_root(lp, p);
                atomicOr(&bc[v >> 5], 1u << (v & 31));
                int rg = origin + (v >> 6) * W_DIM + (v & (TILE - 1));
                int pg = origin + row * W_DIM + lane;
                parent[pg] = rg;
            }
        }
        __syncthreads();
    }

    // ---- Phase C: resolve roots; write labels (MODE1) or parent (MODE0) ----
    #pragma unroll
    for (int j = 0; j < 4; ++j) {
        int s   = t + BLK * j;               // int4 slot in tile
        int row = s >> 4;
        int c4  = s & 15;
        int p0  = row * TILE + c4 * 4;
        int4 q  = reinterpret_cast<const int4*>(lp)[s];
        unsigned fgbits = (unsigned)((rowmask_sh[row] >> (c4 * 4)) & 0xFULL);
        int vr[4];
        {
            int v = q.x, p = p0;
            if ((fgbits & 1u) && v != p) { int w = lp[v]; while (w != v) { v = w; w = lp[v]; } }
            vr[0] = v;
        }
        {
            int v = q.y, p = p0 + 1;
            if ((fgbits & 2u) && v != p) { int w = lp[v]; while (w != v) { v = w; w = lp[v]; } }
            vr[1] = v;
        }
        {
            int v = q.z, p = p0 + 2;
            if ((fgbits & 4u) && v != p) { int w = lp[v]; while (w != v) { v = w; w = lp[v]; } }
            vr[2] = v;
        }
        {
            int v = q.w, p = p0 + 3;
            if ((fgbits & 8u) && v != p) { int w = lp[v]; while (w != v) { v = w; w = lp[v]; } }
            vr[3] = v;
        }

        if constexpr (MODE == 0) {
            int4 o;
            o.x = (fgbits & 1u) ? origin + (vr[0] >> 6) * W_DIM + (vr[0] & (TILE - 1)) : -1;
            o.y = (fgbits & 2u) ? origin + (vr[1] >> 6) * W_DIM + (vr[1] & (TILE - 1)) : -1;
            o.z = (fgbits & 4u) ? origin + (vr[2] >> 6) * W_DIM + (vr[2] & (TILE - 1)) : -1;
            o.w = (fgbits & 8u) ? origin + (vr[3] >> 6) * W_DIM + (vr[3] & (TILE - 1)) : -1;
            reinterpret_cast<int4*>(parent + origin + row * W_DIM)[c4] = o;
        } else {
            float4 o;
            int pg0 = origin + row * W_DIM + c4 * 4;
            #pragma unroll
            for (int k = 0; k < 4; ++k) {
                int v = vr[k];
                bool fg = (fgbits >> k) & 1u;
                int g = origin + (v >> 6) * W_DIM + (v & (TILE - 1));
                float lab = fg ? (float)(MULT - (g & (MULT - 1))) : 0.0f;
                bool nd = fg && ((bc[v >> 5] >> (v & 31)) & 1u);
                if (nd && v == p0 + k) parent[g] = g;    // root self-registers
                if (k == 0) o.x = lab; else if (k == 1) o.y = lab;
                else if (k == 2) o.z = lab; else o.w = lab;
                unsigned long long mask = __ballot(nd);
                if (mask) {
                    int lead = (int)__builtin_ctzll(mask);
                    int cnt  = (int)__popcll(mask);
                    int base = 0;
                    if (lane == lead) base = atomicAdd(&cursor, cnt);
                    base = __shfl(base, lead);
                    if (nd) {
                        int off = base + (int)__popcll(mask & ((1ULL << lane) - 1ULL));
                        int pg = pg0 + k;
                        if (off < WCAP) slabs[tile * WCAP + off] = make_int2(pg, g);
                        else {
                            int oi = atomicAdd(ovf_cnt, 1);
                            if (oi < OVF_CAP) ovf[oi] = make_int2(pg, g);
                        }
                    }
                }
            }
            reinterpret_cast<float4*>(out + origin + row * W_DIM)[c4] = o;
        }
    }
    if constexpr (MODE == 1) {
        __syncthreads();
        if (t == 0) wl_cnt[tile] = (cursor < WCAP) ? cursor : WCAP;
    }
}

__global__ void cc_zero(int* p) { *p = 0; }

// Cross-tile merges; fg from bitmap, UF on sparse parent (endpoints are
// strip pixels -> initialized by cc_local's marking pass).
__global__ __launch_bounds__(BLK) void cc_border_bm(const unsigned long long* __restrict__ bm,
                                                    int* __restrict__ parent, int total) {
    int tid = blockIdx.x * blockDim.x + threadIdx.x;
    if (tid >= total) return;
    const int per_img = 2 * NB * W_DIM;
    int img = tid / per_img;
    int k   = tid % per_img;
    int base = img * MULT;
    const unsigned long long* b = bm + (size_t)img * H_DIM * (W_DIM / 64);
    auto FG = [&](int r, int c) -> bool {
        return (b[r * (W_DIM / 64) + (c >> 6)] >> (c & 63)) & 1ULL;
    };
    if (k < NB * W_DIM) {
        int r = TILE * (1 + k / W_DIM);
        int c = k % W_DIM;
        if (!FG(r, c)) return;
        int i  = base + r * W_DIM + c;
        int up = i - W_DIM;
        if (FG(r - 1, c))                    merge_uf(parent, i, up);
        if (c > 0         && FG(r - 1, c - 1)) merge_uf(parent, i, up - 1);
        if (c < W_DIM - 1 && FG(r - 1, c + 1)) merge_uf(parent, i, up + 1);
    } else {
        int m2 = k - NB * W_DIM;
        int c = TILE * (1 + m2 / H_DIM);
        int r = m2 % H_DIM;
        if (!FG(r, c)) return;
        int i   = base + r * W_DIM + c;
        int lft = i - 1;
        if (FG(r, c - 1))                      merge_uf(parent, i, lft);
        if (r > 0         && FG(r - 1, c - 1)) merge_uf(parent, i, lft - W_DIM);
        if (r < H_DIM - 1 && FG(r + 1, c - 1)) merge_uf(parent, i, lft + W_DIM);
    }
}

// Overwrite labels of border-component pixels with post-merge roots.
__global__ __launch_bounds__(BLK) void cc_fixup(const int2* __restrict__ slabs,
                                                const int* __restrict__ wl_cnt,
                                                const int2* __restrict__ ovf,
                                                const int* __restrict__ ovf_cnt,
                                                const int* __restrict__ parent,
                                                float* __restrict__ out, int ntiles) {
    int tid = blockIdx.x * blockDim.x + threadIdx.x;
    int slab_total = ntiles * WCAP;
    int2 e;
    if (tid < slab_total) {
        int tile = tid / WCAP, slot = tid - tile * WCAP;
        if (slot >= wl_cnt[tile]) return;
        e = slabs[tid];
    } else {
        int oi = tid - slab_total;
        int oc = *ovf_cnt; if (oc > OVF_CAP) oc = OVF_CAP;
        if (oi >= oc) return;
        e = ovf[oi];
    }
    int root = find_root(parent, e.y);
    out[e.x] = (float)(MULT - (root & (MULT - 1)));
}

// ---------------- legacy fallback kernels (round-6 path) ----------------
__global__ __launch_bounds__(BLK) void cc_border(int* __restrict__ parent, int total) {
    int tid = blockIdx.x * blockDim.x + threadIdx.x;
    if (tid >= total) return;
    const int per_img = 2 * NB * W_DIM;
    int img = tid / per_img;
    int k   = tid % per_img;
    int base = img * MULT;
    if (k < NB * W_DIM) {
        int r = TILE * (1 + k / W_DIM);
        int c = k % W_DIM;
        int i = base + r * W_DIM + c;
        if (parent[i] < 0) return;
        int up = i - W_DIM;
        if (parent[up] >= 0)                      merge_uf(parent, i, up);
        if (c > 0         && parent[up - 1] >= 0) merge_uf(parent, i, up - 1);
        if (c < W_DIM - 1 && parent[up + 1] >= 0) merge_uf(parent, i, up + 1);
    } else {
        int m2 = k - NB * W_DIM;
        int c = TILE * (1 + m2 / H_DIM);
        int r = m2 % H_DIM;
        int i = base + r * W_DIM + c;
        if (parent[i] < 0) return;
        int lft = i - 1;
        if (parent[lft] >= 0)                            merge_uf(parent, i, lft);
        if (r > 0         && parent[lft - W_DIM] >= 0)   merge_uf(parent, i, lft - W_DIM);
        if (r < H_DIM - 1 && parent[lft + W_DIM] >= 0)   merge_uf(parent, i, lft + W_DIM);
    }
}

__global__ __launch_bounds__(BLK) void cc_write(const int* __restrict__ parent,
                                                float* __restrict__ out, int n4) {
    int i = blockIdx.x * blockDim.x + threadIdx.x;
    if (i >= n4) return;
    int4 p = reinterpret_cast<const int4*>(parent)[i];
    int a0 = (p.x >= 0) ? parent[p.x] : 0;
    int a1 = (p.y >= 0) ? parent[p.y] : 0;
    int a2 = (p.z >= 0) ? parent[p.z] : 0;
    int a3 = (p.w >= 0) ? parent[p.w] : 0;
    float4 o;
    { int v = p.x, w = a0; if (v >= 0) { while (w != v) { v = w; w = parent[v]; } }
      o.x = (p.x < 0) ? 0.f : (float)(MULT - (v & (MULT - 1))); }
    { int v = p.y, w = a1; if (v >= 0) { while (w != v) { v = w; w = parent[v]; } }
      o.y = (p.y < 0) ? 0.f : (float)(MULT - (v & (MULT - 1))); }
    { int v = p.z, w = a2; if (v >= 0) { while (w != v) { v = w; w = parent[v]; } }
      o.z = (p.z < 0) ? 0.f : (float)(MULT - (v & (MULT - 1))); }
    { int v = p.w, w = a3; if (v >= 0) { while (w != v) { v = w; w = parent[v]; } }
      o.w = (p.w < 0) ? 0.f : (float)(MULT - (v & (MULT - 1))); }
    reinterpret_cast<float4*>(out)[i] = o;
}

__global__ __launch_bounds__(BLK) void cc_flatten(int* __restrict__ parent, int n) {
    int i = blockIdx.x * blockDim.x + threadIdx.x;
    if (i >= n) return;
    int p = parent[i];
    if (p < 0 || p == i) return;
    int r = find_root(parent, p);
    if (r != p) parent[i] = r;
}

__global__ __launch_bounds__(BLK) void cc_final_inplace(int* __restrict__ parent, int n4) {
    int i = blockIdx.x * blockDim.x + threadIdx.x;
    if (i >= n4) return;
    int4 p = reinterpret_cast<const int4*>(parent)[i];
    float4 o;
    o.x = (p.x < 0) ? 0.f : (float)(MULT - (p.x & (MULT - 1)));
    o.y = (p.y < 0) ? 0.f : (float)(MULT - (p.y & (MULT - 1)));
    o.z = (p.z < 0) ? 0.f : (float)(MULT - (p.z & (MULT - 1)));
    o.w = (p.w < 0) ? 0.f : (float)(MULT - (p.w & (MULT - 1)));
    reinterpret_cast<float4*>(parent)[i] = o;
}

extern "C" void kernel_launch(void* const* d_in, const int* in_sizes, int n_in,
                              void* d_out, int out_size, void* d_ws, size_t ws_size,
                              hipStream_t stream) {
    const float* x = (const float*)d_in[0];
    const int n     = in_sizes[0];          // B*H*W
    const int n_img = n / MULT;
    const int n4    = n / 4;
    const int tiles = n_img * TILES_PER_IMG;
    const int border_threads = n_img * 2 * NB * W_DIM;

    // fused-path workspace layout
    size_t off_parent = 0;
    size_t off_bitmap = off_parent + (size_t)n * 4;
    size_t off_slabs  = off_bitmap + (size_t)n / 8;
    size_t off_cnt    = off_slabs  + (size_t)tiles * WCAP * 8;
    size_t off_ovf    = off_cnt    + (size_t)tiles * 4;
    size_t off_ovfcnt = off_ovf    + (size_t)OVF_CAP * 8;
    size_t need_fused = off_ovfcnt + 128;

    dim3 blk(BLK);
    if (ws_size >= need_fused) {
        char* ws = (char*)d_ws;
        int*  parent  = (int*)(ws + off_parent);
        unsigned long long* bitmap = (unsigned long long*)(ws + off_bitmap);
        int2* slabs   = (int2*)(ws + off_slabs);
        int*  wl_cnt  = (int*)(ws + off_cnt);
        int2* ovf     = (int2*)(ws + off_ovf);
        int*  ovf_cnt = (int*)(ws + off_ovfcnt);
        float* out    = (float*)d_out;

        cc_zero<<<1, 1, 0, stream>>>(ovf_cnt);
        cc_local<1><<<tiles, blk, 0, stream>>>(x, parent, out, bitmap,
                                               slabs, wl_cnt, ovf, ovf_cnt);
        cc_border_bm<<<(border_threads + BLK - 1) / BLK, blk, 0, stream>>>(bitmap, parent, border_threads);
        int fix_threads = tiles * WCAP + OVF_CAP;
        cc_fixup<<<(fix_threads + BLK - 1) / BLK, blk, 0, stream>>>(slabs, wl_cnt, ovf, ovf_cnt,
                                                                    parent, out, tiles);
    } else {
        const bool use_ws = (ws_size >= (size_t)n * sizeof(int));
        int* parent = use_ws ? (int*)d_ws : (int*)d_out;
        cc_local<0><<<tiles, blk, 0, stream>>>(x, parent, nullptr, nullptr,
                                               nullptr, nullptr, nullptr, nullptr);
        cc_border<<<(border_threads + BLK - 1) / BLK, blk, 0, stream>>>(parent, border_threads);
        if (use_ws) {
            cc_write<<<(n4 + BLK - 1) / BLK, blk, 0, stream>>>(parent, (float*)d_out, n4);
        } else {
            cc_flatten      <<<(n + BLK - 1) / BLK, blk, 0, stream>>>(parent, n);
            cc_final_inplace<<<(n4 + BLK - 1) / BLK, blk, 0, stream>>>(parent, n4);
        }
    }
}

// Round 8
// 64.042 us; speedup vs baseline: 1.6036x; 1.0648x over previous
//
#include <hip/hip_runtime.h>

// Two-level connected components, fused output:
//  - cc_local: per-tile union-find in LDS (ballot row masks, scalar mask
//    algebra, batched merge drain). Writes FINAL labels to out directly.
//    Border-component bookkeeping is cheap: wave-parallel strip marking
//    (each wave owns one strip edge) + deferred per-thread worklist
//    compaction (one LDS atomic per thread that owns any border pixel).
//  - cc_border_bm: cross-tile merges; fg tests from a 2MB bitmap,
//    union-find on the sparse parent (endpoints are strip pixels).
//  - cc_fixup: walks worklist entries only (~1.5% of pixels), overwrites
//    their labels with the post-merge root.
//
// Label semantics: out = MULT - min(local linear index over 8-conn component)
// for foreground, 0 for background.
//
// UF invariant: parent[v] <= v, every stored value is a true ancestor ->
// atomicMin linking converges to exact min-index roots (verified r1-r7).

constexpr int W_DIM = 2048;
constexpr int H_DIM = 2048;
constexpr int MULT  = W_DIM * H_DIM;        // 2^22 pixels per image
constexpr int TILE  = 64;
constexpr int TPX   = TILE * TILE;          // 4096 pixels per tile
constexpr int BLK   = 256;                  // 4 waves
constexpr int TILES_PER_IMG = MULT / TPX;   // 1024
constexpr int NB    = (H_DIM / TILE) - 1;   // 31 interior boundaries per dim
constexpr int WCAP  = 512;                  // per-tile worklist capacity
constexpr int OVF_CAP = 65536;              // global overflow capacity

__device__ __forceinline__ int find_root(const int* p, int v) {
    int q = p[v];
    while (q != v) { v = q; q = p[v]; }
    return v;
}

__device__ __forceinline__ void merge_uf(int* p, int a, int b) {
    while (true) {
        a = find_root(p, a);
        b = find_root(p, b);
        if (a == b) return;
        if (a < b) { int t = a; a = b; b = t; }  // a > b
        int old = atomicMin(&p[a], b);
        if (old == a) return;                    // a was root; linked under b
        a = old;                                 // displaced; retry from old
    }
}

// MODE 0: legacy (write full parent). MODE 1: fused (write out + sparse UF).
template <int MODE>
__global__ __launch_bounds__(BLK) void cc_local(const float* __restrict__ x,
                                                int* __restrict__ parent,
                                                float* __restrict__ out,
                                                unsigned long long* __restrict__ bitmap,
                                                int2* __restrict__ slabs,
                                                int* __restrict__ wl_cnt,
                                                int2* __restrict__ ovf,
                                                int* __restrict__ ovf_cnt) {
    __shared__ int lp[TPX];
    __shared__ unsigned long long rowmask_sh[TILE];
    __shared__ unsigned int bc[TPX / 32];    // border-component root bitset
    __shared__ int cursor;

    const int t    = threadIdx.x;
    const int wave = t >> 6;                 // 0..3
    const int lane = t & 63;
    const int tile = blockIdx.x;
    const int img  = tile / TILES_PER_IMG;
    const int tl   = tile % TILES_PER_IMG;
    const int tr   = tl >> 5;                // 32 tile cols per image row
    const int tc   = tl & 31;
    const int origin = img * MULT + (tr * TILE) * W_DIM + tc * TILE;

    // ---- Phase A: load x, ballot row bitmaps, init lp / bc / cursor ----
    unsigned long long m[16];
    #pragma unroll
    for (int rr = 0; rr < 16; ++rr) {
        int row = wave * 16 + rr;
        float v = x[origin + row * W_DIM + lane];
        m[rr] = __ballot(v != 0.0f);
    }
    if (lane == 0) {
        #pragma unroll
        for (int rr = 0; rr < 16; ++rr) {
            rowmask_sh[wave * 16 + rr] = m[rr];
            if constexpr (MODE == 1) {
                int grow = tr * TILE + wave * 16 + rr;
                bitmap[(img * H_DIM + grow) * (W_DIM / 64) + tc] = m[rr];
            }
        }
    }
    if constexpr (MODE == 1) {
        if (t < TPX / 32) bc[t] = 0u;
        if (t == 0) cursor = 0;
    }
    #pragma unroll
    for (int j = 0; j < 4; ++j) {
        int s = t + BLK * j;
        int b = s * 4;
        reinterpret_cast<int4*>(lp)[s] = make_int4(b, b + 1, b + 2, b + 3);
    }
    __syncthreads();

    const unsigned long long mu0 = (wave > 0) ? rowmask_sh[wave * 16 - 1] : 0ULL;

    // ---- Phase B1: per-lane merge bitset (bit 4*rr+type) ----
    unsigned long long bits = 0ULL;
    #pragma unroll
    for (int rr = 0; rr < 16; ++rr) {
        const unsigned long long mm = m[rr];
        const unsigned long long mu = (rr == 0) ? mu0 : m[rr - 1];
        const unsigned long long lmask  = mm & (mm << 1);
        const unsigned long long bfmask = mm & mu & ~((mm << 1) & (mu << 1));
        const unsigned long long afmask = mm & (mu << 1) & ~mu & ~(mm << 1);
        const unsigned long long cfmask = mm & (mu >> 1) & ~mu;
        unsigned nib = (unsigned)((lmask  >> lane) & 1ULL)
                     | ((unsigned)((bfmask >> lane) & 1ULL) << 1)
                     | ((unsigned)((afmask >> lane) & 1ULL) << 2)
                     | ((unsigned)((cfmask >> lane) & 1ULL) << 3);
        bits |= (unsigned long long)nib << (rr * 4);
    }

    // ---- Phase B2: batched merge drain ----
    while (__any(bits != 0ULL)) {
        if (bits) {
            int idx = (int)__builtin_ctzll(bits);
            bits &= bits - 1;
            int rr = idx >> 2, ty = idx & 3;
            int p  = (wave * 16 + rr) * TILE + lane;
            int off = (ty & 2) ? ((ty & 1) ? -(TILE - 1) : -(TILE + 1))
                               : ((ty & 1) ? -TILE : -1);
            merge_uf(lp, p, p + off);
        }
    }
    __syncthreads();

    // ---- Marking pass (MODE 1): wave-parallel strip marking. Each wave
    // owns one strip edge; every lane handles <=1 pixel concurrently.
    // Corner pixels are handled by two waves -> identical writes, benign.
    if constexpr (MODE == 1) {
        int p = -1;
        bool mark = false;
        if      (wave == 0) { if (tr > 0)  { p = lane;                      mark = (rowmask_sh[0]    >> lane) & 1ULL; } }
        else if (wave == 3) { if (tr < 31) { p = (TILE - 1) * TILE + lane;  mark = (rowmask_sh[63]   >> lane) & 1ULL; } }
        else if (wave == 1) { if (tc > 0)  { p = lane * TILE;               mark = rowmask_sh[lane] & 1ULL; } }
        else                { if (tc < 31) { p = lane * TILE + (TILE - 1);  mark = (rowmask_sh[lane] >> 63) & 1ULL; } }
        if (mark) {
            int v = find_root(lp, p);
            atomicOr(&bc[v >> 5], 1u << (v & 31));
            int rg = origin + (v >> 6) * W_DIM + (v & (TILE - 1));
            int pg = origin + (p >> 6) * W_DIM + (p & (TILE - 1));
            parent[pg] = rg;
        }
        __syncthreads();
    }

    // ---- Phase C: resolve roots; write labels (MODE1) or parent (MODE0).
    // Border-pixel worklist entries are DEFERRED: just set a bit now. ----
    unsigned ndbits = 0;
    #pragma unroll
    for (int j = 0; j < 4; ++j) {
        int s   = t + BLK * j;               // int4 slot in tile
        int row = s >> 4;
        int c4  = s & 15;
        int p0  = row * TILE + c4 * 4;
        int4 q  = reinterpret_cast<const int4*>(lp)[s];
        unsigned fgbits = (unsigned)((rowmask_sh[row] >> (c4 * 4)) & 0xFULL);
        int vr[4];
        {
            int v = q.x, p = p0;
            if ((fgbits & 1u) && v != p) { int w = lp[v]; while (w != v) { v = w; w = lp[v]; } }
            vr[0] = v;
        }
        {
            int v = q.y, p = p0 + 1;
            if ((fgbits & 2u) && v != p) { int w = lp[v]; while (w != v) { v = w; w = lp[v]; } }
            vr[1] = v;
        }
        {
            int v = q.z, p = p0 + 2;
            if ((fgbits & 4u) && v != p) { int w = lp[v]; while (w != v) { v = w; w = lp[v]; } }
            vr[2] = v;
        }
        {
            int v = q.w, p = p0 + 3;
            if ((fgbits & 8u) && v != p) { int w = lp[v]; while (w != v) { v = w; w = lp[v]; } }
            vr[3] = v;
        }

        if constexpr (MODE == 0) {
            int4 o;
            o.x = (fgbits & 1u) ? origin + (vr[0] >> 6) * W_DIM + (vr[0] & (TILE - 1)) : -1;
            o.y = (fgbits & 2u) ? origin + (vr[1] >> 6) * W_DIM + (vr[1] & (TILE - 1)) : -1;
            o.z = (fgbits & 4u) ? origin + (vr[2] >> 6) * W_DIM + (vr[2] & (TILE - 1)) : -1;
            o.w = (fgbits & 8u) ? origin + (vr[3] >> 6) * W_DIM + (vr[3] & (TILE - 1)) : -1;
            reinterpret_cast<int4*>(parent + origin + row * W_DIM)[c4] = o;
        } else {
            float4 o;
            float lab[4];
            #pragma unroll
            for (int k = 0; k < 4; ++k) {
                int v = vr[k];
                bool fg = (fgbits >> k) & 1u;
                int g = origin + (v >> 6) * W_DIM + (v & (TILE - 1));
                lab[k] = fg ? (float)(MULT - (g & (MULT - 1))) : 0.0f;
                bool nd = fg && ((bc[v >> 5] >> (v & 31)) & 1u);
                if (nd) {
                    ndbits |= 1u << (j * 4 + k);
                    if (v == p0 + k) parent[g] = g;      // root self-registers
                }
            }
            o.x = lab[0]; o.y = lab[1]; o.z = lab[2]; o.w = lab[3];
            reinterpret_cast<float4*>(out + origin + row * W_DIM)[c4] = o;
        }
    }

    if constexpr (MODE == 1) {
        // ---- Deferred worklist append: one LDS atomic per thread with work.
        if (ndbits) {
            int cnt  = __popc(ndbits);
            int base = atomicAdd(&cursor, cnt);
            while (ndbits) {
                int b = (int)__builtin_ctz(ndbits);
                ndbits &= ndbits - 1;
                int j = b >> 2, k = b & 3;
                int s   = t + BLK * j;
                int row = s >> 4;
                int c4  = s & 15;
                int p   = row * TILE + c4 * 4 + k;
                int v   = find_root(lp, p);              // short re-walk
                int g   = origin + (v >> 6) * W_DIM + (v & (TILE - 1));
                int pg  = origin + row * W_DIM + c4 * 4 + k;
                int off = base++;
                if (off < WCAP) slabs[tile * WCAP + off] = make_int2(pg, g);
                else {
                    int oi = atomicAdd(ovf_cnt, 1);
                    if (oi < OVF_CAP) ovf[oi] = make_int2(pg, g);
                }
            }
        }
        __syncthreads();
        if (t == 0) wl_cnt[tile] = (cursor < WCAP) ? cursor : WCAP;
    }
}

__global__ void cc_zero(int* p) { *p = 0; }

// Cross-tile merges; fg from bitmap, UF on sparse parent (endpoints are
// strip pixels -> initialized by cc_local's marking pass).
__global__ __launch_bounds__(BLK) void cc_border_bm(const unsigned long long* __restrict__ bm,
                                                    int* __restrict__ parent, int total) {
    int tid = blockIdx.x * blockDim.x + threadIdx.x;
    if (tid >= total) return;
    const int per_img = 2 * NB * W_DIM;
    int img = tid / per_img;
    int k   = tid % per_img;
    int base = img * MULT;
    const unsigned long long* b = bm + (size_t)img * H_DIM * (W_DIM / 64);
    auto FG = [&](int r, int c) -> bool {
        return (b[r * (W_DIM / 64) + (c >> 6)] >> (c & 63)) & 1ULL;
    };
    if (k < NB * W_DIM) {
        int r = TILE * (1 + k / W_DIM);
        int c = k % W_DIM;
        if (!FG(r, c)) return;
        int i  = base + r * W_DIM + c;
        int up = i - W_DIM;
        if (FG(r - 1, c))                    merge_uf(parent, i, up);
        if (c > 0         && FG(r - 1, c - 1)) merge_uf(parent, i, up - 1);
        if (c < W_DIM - 1 && FG(r - 1, c + 1)) merge_uf(parent, i, up + 1);
    } else {
        int m2 = k - NB * W_DIM;
        int c = TILE * (1 + m2 / H_DIM);
        int r = m2 % H_DIM;
        if (!FG(r, c)) return;
        int i   = base + r * W_DIM + c;
        int lft = i - 1;
        if (FG(r, c - 1))                      merge_uf(parent, i, lft);
        if (r > 0         && FG(r - 1, c - 1)) merge_uf(parent, i, lft - W_DIM);
        if (r < H_DIM - 1 && FG(r + 1, c - 1)) merge_uf(parent, i, lft + W_DIM);
    }
}

// Overwrite labels of border-component pixels with post-merge roots.
__global__ __launch_bounds__(BLK) void cc_fixup(const int2* __restrict__ slabs,
                                                const int* __restrict__ wl_cnt,
                                                const int2* __restrict__ ovf,
                                                const int* __restrict__ ovf_cnt,
                                                const int* __restrict__ parent,
                                                float* __restrict__ out, int ntiles) {
    int tid = blockIdx.x * blockDim.x + threadIdx.x;
    int slab_total = ntiles * WCAP;
    int2 e;
    if (tid < slab_total) {
        int tile = tid / WCAP, slot = tid - tile * WCAP;
        if (slot >= wl_cnt[tile]) return;
        e = slabs[tid];
    } else {
        int oi = tid - slab_total;
        int oc = *ovf_cnt; if (oc > OVF_CAP) oc = OVF_CAP;
        if (oi >= oc) return;
        e = ovf[oi];
    }
    int root = find_root(parent, e.y);
    out[e.x] = (float)(MULT - (root & (MULT - 1)));
}

// ---------------- legacy fallback kernels (round-6 path) ----------------
__global__ __launch_bounds__(BLK) void cc_border(int* __restrict__ parent, int total) {
    int tid = blockIdx.x * blockDim.x + threadIdx.x;
    if (tid >= total) return;
    const int per_img = 2 * NB * W_DIM;
    int img = tid / per_img;
    int k   = tid % per_img;
    int base = img * MULT;
    if (k < NB * W_DIM) {
        int r = TILE * (1 + k / W_DIM);
        int c = k % W_DIM;
        int i = base + r * W_DIM + c;
        if (parent[i] < 0) return;
        int up = i - W_DIM;
        if (parent[up] >= 0)                      merge_uf(parent, i, up);
        if (c > 0         && parent[up - 1] >= 0) merge_uf(parent, i, up - 1);
        if (c < W_DIM - 1 && parent[up + 1] >= 0) merge_uf(parent, i, up + 1);
    } else {
        int m2 = k - NB * W_DIM;
        int c = TILE * (1 + m2 / H_DIM);
        int r = m2 % H_DIM;
        int i = base + r * W_DIM + c;
        if (parent[i] < 0) return;
        int lft = i - 1;
        if (parent[lft] >= 0)                            merge_uf(parent, i, lft);
        if (r > 0         && parent[lft - W_DIM] >= 0)   merge_uf(parent, i, lft - W_DIM);
        if (r < H_DIM - 1 && parent[lft + W_DIM] >= 0)   merge_uf(parent, i, lft + W_DIM);
    }
}

__global__ __launch_bounds__(BLK) void cc_write(const int* __restrict__ parent,
                                                float* __restrict__ out, int n4) {
    int i = blockIdx.x * blockDim.x + threadIdx.x;
    if (i >= n4) return;
    int4 p = reinterpret_cast<const int4*>(parent)[i];
    int a0 = (p.x >= 0) ? parent[p.x] : 0;
    int a1 = (p.y >= 0) ? parent[p.y] : 0;
    int a2 = (p.z >= 0) ? parent[p.z] : 0;
    int a3 = (p.w >= 0) ? parent[p.w] : 0;
    float4 o;
    { int v = p.x, w = a0; if (v >= 0) { while (w != v) { v = w; w = parent[v]; } }
      o.x = (p.x < 0) ? 0.f : (float)(MULT - (v & (MULT - 1))); }
    { int v = p.y, w = a1; if (v >= 0) { while (w != v) { v = w; w = parent[v]; } }
      o.y = (p.y < 0) ? 0.f : (float)(MULT - (v & (MULT - 1))); }
    { int v = p.z, w = a2; if (v >= 0) { while (w != v) { v = w; w = parent[v]; } }
      o.z = (p.z < 0) ? 0.f : (float)(MULT - (v & (MULT - 1))); }
    { int v = p.w, w = a3; if (v >= 0) { while (w != v) { v = w; w = parent[v]; } }
      o.w = (p.w < 0) ? 0.f : (float)(MULT - (v & (MULT - 1))); }
    reinterpret_cast<float4*>(out)[i] = o;
}

__global__ __launch_bounds__(BLK) void cc_flatten(int* __restrict__ parent, int n) {
    int i = blockIdx.x * blockDim.x + threadIdx.x;
    if (i >= n) return;
    int p = parent[i];
    if (p < 0 || p == i) return;
    int r = find_root(parent, p);
    if (r != p) parent[i] = r;
}

__global__ __launch_bounds__(BLK) void cc_final_inplace(int* __restrict__ parent, int n4) {
    int i = blockIdx.x * blockDim.x + threadIdx.x;
    if (i >= n4) return;
    int4 p = reinterpret_cast<const int4*>(parent)[i];
    float4 o;
    o.x = (p.x < 0) ? 0.f : (float)(MULT - (p.x & (MULT - 1)));
    o.y = (p.y < 0) ? 0.f : (float)(MULT - (p.y & (MULT - 1)));
    o.z = (p.z < 0) ? 0.f : (float)(MULT - (p.z & (MULT - 1)));
    o.w = (p.w < 0) ? 0.f : (float)(MULT - (p.w & (MULT - 1)));
    reinterpret_cast<float4*>(parent)[i] = o;
}

extern "C" void kernel_launch(void* const* d_in, const int* in_sizes, int n_in,
                              void* d_out, int out_size, void* d_ws, size_t ws_size,
                              hipStream_t stream) {
    const float* x = (const float*)d_in[0];
    const int n     = in_sizes[0];          // B*H*W
    const int n_img = n / MULT;
    const int n4    = n / 4;
    const int tiles = n_img * TILES_PER_IMG;
    const int border_threads = n_img * 2 * NB * W_DIM;

    // fused-path workspace layout
    size_t off_parent = 0;
    size_t off_bitmap = off_parent + (size_t)n * 4;
    size_t off_slabs  = off_bitmap + (size_t)n / 8;
    size_t off_cnt    = off_slabs  + (size_t)tiles * WCAP * 8;
    size_t off_ovf    = off_cnt    + (size_t)tiles * 4;
    size_t off_ovfcnt = off_ovf    + (size_t)OVF_CAP * 8;
    size_t need_fused = off_ovfcnt + 128;

    dim3 blk(BLK);
    if (ws_size >= need_fused) {
        char* ws = (char*)d_ws;
        int*  parent  = (int*)(ws + off_parent);
        unsigned long long* bitmap = (unsigned long long*)(ws + off_bitmap);
        int2* slabs   = (int2*)(ws + off_slabs);
        int*  wl_cnt  = (int*)(ws + off_cnt);
        int2* ovf     = (int2*)(ws + off_ovf);
        int*  ovf_cnt = (int*)(ws + off_ovfcnt);
        float* out    = (float*)d_out;

        cc_zero<<<1, 1, 0, stream>>>(ovf_cnt);
        cc_local<1><<<tiles, blk, 0, stream>>>(x, parent, out, bitmap,
                                               slabs, wl_cnt, ovf, ovf_cnt);
        cc_border_bm<<<(border_threads + BLK - 1) / BLK, blk, 0, stream>>>(bitmap, parent, border_threads);
        int fix_threads = tiles * WCAP + OVF_CAP;
        cc_fixup<<<(fix_threads + BLK - 1) / BLK, blk, 0, stream>>>(slabs, wl_cnt, ovf, ovf_cnt,
                                                                    parent, out, tiles);
    } else {
        const bool use_ws = (ws_size >= (size_t)n * sizeof(int));
        int* parent = use_ws ? (int*)d_ws : (int*)d_out;
        cc_local<0><<<tiles, blk, 0, stream>>>(x, parent, nullptr, nullptr,
                                               nullptr, nullptr, nullptr, nullptr);
        cc_border<<<(border_threads + BLK - 1) / BLK, blk, 0, stream>>>(parent, border_threads);
        if (use_ws) {
            cc_write<<<(n4 + BLK - 1) / BLK, blk, 0, stream>>>(parent, (float*)d_out, n4);
        } else {
            cc_flatten      <<<(n + BLK - 1) / BLK, blk, 0, stream>>>(parent, n);
            cc_final_inplace<<<(n4 + BLK - 1) / BLK, blk, 0, stream>>>(parent, n4);
        }
    }
}

// Round 9
// 60.427 us; speedup vs baseline: 1.6995x; 1.0598x over previous
//
#include <hip/hip_runtime.h>

// Two-level connected components, fused output.
//  - cc_local: per-tile union-find in LDS (ballot row masks, scalar mask
//    algebra, batched merge drain). Border-component roots are flagged IN
//    lp (bit 16) by a wave-parallel marking pass, so Phase C's root walk
//    picks up the flag for free; flagged pixels append (pixel,root) to a
//    per-tile worklist slab inline. Final labels stream to out.
//  - cc_border_bm: cross-tile merges; fg tests from a 2MB bitmap,
//    union-find on the sparse parent (endpoints = strip pixels + roots).
//  - cc_fixup: walks worklist entries only (~1.5% of pixels), rewrites
//    labels whose root changed.
//
// Label semantics: out = MULT - min(local linear index over 8-conn component)
// for foreground, 0 for background.
//
// UF invariant: parent[v] <= v, every stored value is a true ancestor ->
// atomicMin linking converges to exact min-index roots (verified r1-r8).
// lp encoding: low 16 bits = parent (0..4095); bit 16 = border flag, set
// ONLY on final roots (after the drain barrier, before Phase C).

constexpr int W_DIM = 2048;
constexpr int H_DIM = 2048;
constexpr int MULT  = W_DIM * H_DIM;        // 2^22 pixels per image
constexpr int TILE  = 64;
constexpr int TPX   = TILE * TILE;          // 4096 pixels per tile
constexpr int BLK   = 256;                  // 4 waves
constexpr int TILES_PER_IMG = MULT / TPX;   // 1024
constexpr int NB    = (H_DIM / TILE) - 1;   // 31 interior boundaries per dim
constexpr int WCAP  = 512;                  // per-tile worklist capacity
constexpr int OVF_CAP = 65536;              // global overflow capacity
constexpr int PMASK = 0xFFFF;               // lp parent field
constexpr int BFLAG = 0x10000;              // lp border flag (roots only)

__device__ __forceinline__ int find_root(const int* p, int v) {
    int q = p[v];
    while (q != v) { v = q; q = p[v]; }
    return v;
}

// flag-tolerant find (marking pass: flags may appear concurrently on roots)
__device__ __forceinline__ int find_root_m(const int* p, int v) {
    int q = p[v] & PMASK;
    while (q != v) { v = q; q = p[v] & PMASK; }
    return v;
}

__device__ __forceinline__ void merge_uf(int* p, int a, int b) {
    while (true) {
        a = find_root(p, a);
        b = find_root(p, b);
        if (a == b) return;
        if (a < b) { int t = a; a = b; b = t; }  // a > b
        int old = atomicMin(&p[a], b);
        if (old == a) return;                    // a was root; linked under b
        a = old;                                 // displaced; retry from old
    }
}

// MODE 0: legacy (write full parent). MODE 1: fused (write out + sparse UF).
template <int MODE>
__global__ __launch_bounds__(BLK) void cc_local(const float* __restrict__ x,
                                                int* __restrict__ parent,
                                                float* __restrict__ out,
                                                unsigned long long* __restrict__ bitmap,
                                                int2* __restrict__ slabs,
                                                int* __restrict__ wl_cnt,
                                                int2* __restrict__ ovf,
                                                int* __restrict__ ovf_cnt) {
    __shared__ int lp[TPX];
    __shared__ unsigned long long rowmask_sh[TILE];
    __shared__ int cursor;

    const int t    = threadIdx.x;
    const int wave = t >> 6;                 // 0..3
    const int lane = t & 63;
    const int tile = blockIdx.x;
    const int img  = tile / TILES_PER_IMG;
    const int tl   = tile % TILES_PER_IMG;
    const int tr   = tl >> 5;                // 32 tile cols per image row
    const int tc   = tl & 31;
    const int origin    = img * MULT + (tr * TILE) * W_DIM + tc * TILE;
    const int img_base  = img * MULT;
    const int base_loc  = origin - img_base; // tile origin, local-in-image

    // ---- Phase A: load x, ballot row bitmaps, init lp / cursor ----
    unsigned long long m[16];
    #pragma unroll
    for (int rr = 0; rr < 16; ++rr) {
        int row = wave * 16 + rr;
        float v = x[origin + row * W_DIM + lane];
        m[rr] = __ballot(v != 0.0f);
    }
    if (lane == 0) {
        #pragma unroll
        for (int rr = 0; rr < 16; ++rr) {
            rowmask_sh[wave * 16 + rr] = m[rr];
            if constexpr (MODE == 1) {
                int grow = tr * TILE + wave * 16 + rr;
                bitmap[(img * H_DIM + grow) * (W_DIM / 64) + tc] = m[rr];
            }
        }
    }
    if constexpr (MODE == 1) {
        if (t == 0) cursor = 0;
    }
    #pragma unroll
    for (int j = 0; j < 4; ++j) {
        int s = t + BLK * j;
        int b = s * 4;
        reinterpret_cast<int4*>(lp)[s] = make_int4(b, b + 1, b + 2, b + 3);
    }
    __syncthreads();

    const unsigned long long mu0 = (wave > 0) ? rowmask_sh[wave * 16 - 1] : 0ULL;

    // ---- Phase B1: per-lane merge bitset (bit 4*rr+type) ----
    unsigned long long bits = 0ULL;
    #pragma unroll
    for (int rr = 0; rr < 16; ++rr) {
        const unsigned long long mm = m[rr];
        const unsigned long long mu = (rr == 0) ? mu0 : m[rr - 1];
        const unsigned long long lmask  = mm & (mm << 1);
        const unsigned long long bfmask = mm & mu & ~((mm << 1) & (mu << 1));
        const unsigned long long afmask = mm & (mu << 1) & ~mu & ~(mm << 1);
        const unsigned long long cfmask = mm & (mu >> 1) & ~mu;
        unsigned nib = (unsigned)((lmask  >> lane) & 1ULL)
                     | ((unsigned)((bfmask >> lane) & 1ULL) << 1)
                     | ((unsigned)((afmask >> lane) & 1ULL) << 2)
                     | ((unsigned)((cfmask >> lane) & 1ULL) << 3);
        bits |= (unsigned long long)nib << (rr * 4);
    }

    // ---- Phase B2: batched merge drain (no flags exist yet) ----
    while (__any(bits != 0ULL)) {
        if (bits) {
            int idx = (int)__builtin_ctzll(bits);
            bits &= bits - 1;
            int rr = idx >> 2, ty = idx & 3;
            int p  = (wave * 16 + rr) * TILE + lane;
            int off = (ty & 2) ? ((ty & 1) ? -(TILE - 1) : -(TILE + 1))
                               : ((ty & 1) ? -TILE : -1);
            merge_uf(lp, p, p + off);
        }
    }
    __syncthreads();

    // ---- Marking (MODE 1): wave-parallel strip marking. Flag the root in
    // lp (bit 16) and seed the sparse global parent (pixel + root). ----
    if constexpr (MODE == 1) {
        int p = -1;
        bool mark = false;
        if      (wave == 0) { if (tr > 0)  { p = lane;                      mark = (rowmask_sh[0]    >> lane) & 1ULL; } }
        else if (wave == 3) { if (tr < 31) { p = (TILE - 1) * TILE + lane;  mark = (rowmask_sh[63]   >> lane) & 1ULL; } }
        else if (wave == 1) { if (tc > 0)  { p = lane * TILE;               mark = rowmask_sh[lane] & 1ULL; } }
        else                { if (tc < 31) { p = lane * TILE + (TILE - 1);  mark = (rowmask_sh[lane] >> 63) & 1ULL; } }
        if (mark) {
            int v = find_root_m(lp, p);
            atomicOr(&lp[v], BFLAG);
            int rg = origin + (v >> 6) * W_DIM + (v & (TILE - 1));
            int pg = origin + (p >> 6) * W_DIM + (p & (TILE - 1));
            parent[pg] = rg;
            parent[rg] = rg;
        }
        __syncthreads();
    }

    // ---- Phase C: root walk (flag rides the final read), write labels
    // (MODE1) or parent (MODE0); flagged pixels append inline. ----
    #pragma unroll
    for (int j = 0; j < 4; ++j) {
        int s   = t + BLK * j;               // int4 slot in tile
        int row = s >> 4;
        int c4  = s & 15;
        int p0  = row * TILE + c4 * 4;
        int4 qv = reinterpret_cast<const int4*>(lp)[s];
        unsigned fgbits = (unsigned)((rowmask_sh[row] >> (c4 * 4)) & 0xFULL);
        int vr[4], qf[4];
        {
            int q = qv.x, v = q & PMASK, p = p0;
            if ((fgbits & 1u) && v != p) {
                int w = lp[v];
                while ((w & PMASK) != v) { v = w & PMASK; w = lp[v]; }
                q = w;
            }
            vr[0] = v; qf[0] = q;
        }
        {
            int q = qv.y, v = q & PMASK, p = p0 + 1;
            if ((fgbits & 2u) && v != p) {
                int w = lp[v];
                while ((w & PMASK) != v) { v = w & PMASK; w = lp[v]; }
                q = w;
            }
            vr[1] = v; qf[1] = q;
        }
        {
            int q = qv.z, v = q & PMASK, p = p0 + 2;
            if ((fgbits & 4u) && v != p) {
                int w = lp[v];
                while ((w & PMASK) != v) { v = w & PMASK; w = lp[v]; }
                q = w;
            }
            vr[2] = v; qf[2] = q;
        }
        {
            int q = qv.w, v = q & PMASK, p = p0 + 3;
            if ((fgbits & 8u) && v != p) {
                int w = lp[v];
                while ((w & PMASK) != v) { v = w & PMASK; w = lp[v]; }
                q = w;
            }
            vr[3] = v; qf[3] = q;
        }

        if constexpr (MODE == 0) {
            int4 o;
            o.x = (fgbits & 1u) ? origin + (vr[0] >> 6) * W_DIM + (vr[0] & (TILE - 1)) : -1;
            o.y = (fgbits & 2u) ? origin + (vr[1] >> 6) * W_DIM + (vr[1] & (TILE - 1)) : -1;
            o.z = (fgbits & 4u) ? origin + (vr[2] >> 6) * W_DIM + (vr[2] & (TILE - 1)) : -1;
            o.w = (fgbits & 8u) ? origin + (vr[3] >> 6) * W_DIM + (vr[3] & (TILE - 1)) : -1;
            reinterpret_cast<int4*>(parent + origin + row * W_DIM)[c4] = o;
        } else {
            float lab[4];
            #pragma unroll
            for (int k = 0; k < 4; ++k) {
                int v  = vr[k];
                bool fg = (fgbits >> k) & 1u;
                int rl = base_loc + ((v >> 6) << 11) + (v & (TILE - 1)); // root, local-in-image
                lab[k] = fg ? (float)(MULT - rl) : 0.0f;
                if (fg && (qf[k] & BFLAG)) {                 // border component
                    int off = atomicAdd(&cursor, 1);
                    int pg  = origin + row * W_DIM + c4 * 4 + k;
                    int g   = img_base + rl;
                    if (off < WCAP) slabs[tile * WCAP + off] = make_int2(pg, g);
                    else {
                        int oi = atomicAdd(ovf_cnt, 1);
                        if (oi < OVF_CAP) ovf[oi] = make_int2(pg, g);
                    }
                }
            }
            float4 o; o.x = lab[0]; o.y = lab[1]; o.z = lab[2]; o.w = lab[3];
            reinterpret_cast<float4*>(out + origin + row * W_DIM)[c4] = o;
        }
    }

    if constexpr (MODE == 1) {
        __syncthreads();
        if (t == 0) wl_cnt[tile] = (cursor < WCAP) ? cursor : WCAP;
    }
}

// Cross-tile merges; fg from bitmap, UF on sparse parent (endpoints are
// strip pixels -> initialized by cc_local's marking pass).
__global__ __launch_bounds__(BLK) void cc_border_bm(const unsigned long long* __restrict__ bm,
                                                    int* __restrict__ parent, int total) {
    int tid = blockIdx.x * blockDim.x + threadIdx.x;
    if (tid >= total) return;
    const int per_img = 2 * NB * W_DIM;
    int img = tid / per_img;
    int k   = tid % per_img;
    int base = img * MULT;
    const unsigned long long* b = bm + (size_t)img * H_DIM * (W_DIM / 64);
    auto FG = [&](int r, int c) -> bool {
        return (b[r * (W_DIM / 64) + (c >> 6)] >> (c & 63)) & 1ULL;
    };
    if (k < NB * W_DIM) {
        int r = TILE * (1 + k / W_DIM);
        int c = k % W_DIM;
        if (!FG(r, c)) return;
        int i  = base + r * W_DIM + c;
        int up = i - W_DIM;
        if (FG(r - 1, c))                      merge_uf(parent, i, up);
        if (c > 0         && FG(r - 1, c - 1)) merge_uf(parent, i, up - 1);
        if (c < W_DIM - 1 && FG(r - 1, c + 1)) merge_uf(parent, i, up + 1);
    } else {
        int m2 = k - NB * W_DIM;
        int c = TILE * (1 + m2 / H_DIM);
        int r = m2 % H_DIM;
        if (!FG(r, c)) return;
        int i   = base + r * W_DIM + c;
        int lft = i - 1;
        if (FG(r, c - 1))                      merge_uf(parent, i, lft);
        if (r > 0         && FG(r - 1, c - 1)) merge_uf(parent, i, lft - W_DIM);
        if (r < H_DIM - 1 && FG(r + 1, c - 1)) merge_uf(parent, i, lft + W_DIM);
    }
}

// Rewrite labels of border-component pixels whose root changed.
__global__ __launch_bounds__(BLK) void cc_fixup(const int2* __restrict__ slabs,
                                                const int* __restrict__ wl_cnt,
                                                const int2* __restrict__ ovf,
                                                const int* __restrict__ ovf_cnt,
                                                const int* __restrict__ parent,
                                                float* __restrict__ out, int ntiles) {
    int tid = blockIdx.x * blockDim.x + threadIdx.x;
    int slab_total = ntiles * WCAP;
    int2 e;
    if (tid < slab_total) {
        int tile = tid / WCAP, slot = tid - tile * WCAP;
        if (slot >= wl_cnt[tile]) return;
        e = slabs[tid];
    } else {
        int oi = tid - slab_total;
        int oc = *ovf_cnt; if (oc > OVF_CAP) oc = OVF_CAP;
        if (oi >= oc) return;
        e = ovf[oi];
    }
    int root = find_root(parent, e.y);
    if (root != e.y) out[e.x] = (float)(MULT - (root & (MULT - 1)));
}

// ---------------- legacy fallback kernels ----------------
__global__ __launch_bounds__(BLK) void cc_border(int* __restrict__ parent, int total) {
    int tid = blockIdx.x * blockDim.x + threadIdx.x;
    if (tid >= total) return;
    const int per_img = 2 * NB * W_DIM;
    int img = tid / per_img;
    int k   = tid % per_img;
    int base = img * MULT;
    if (k < NB * W_DIM) {
        int r = TILE * (1 + k / W_DIM);
        int c = k % W_DIM;
        int i = base + r * W_DIM + c;
        if (parent[i] < 0) return;
        int up = i - W_DIM;
        if (parent[up] >= 0)                      merge_uf(parent, i, up);
        if (c > 0         && parent[up - 1] >= 0) merge_uf(parent, i, up - 1);
        if (c < W_DIM - 1 && parent[up + 1] >= 0) merge_uf(parent, i, up + 1);
    } else {
        int m2 = k - NB * W_DIM;
        int c = TILE * (1 + m2 / H_DIM);
        int r = m2 % H_DIM;
        int i = base + r * W_DIM + c;
        if (parent[i] < 0) return;
        int lft = i - 1;
        if (parent[lft] >= 0)                            merge_uf(parent, i, lft);
        if (r > 0         && parent[lft - W_DIM] >= 0)   merge_uf(parent, i, lft - W_DIM);
        if (r < H_DIM - 1 && parent[lft + W_DIM] >= 0)   merge_uf(parent, i, lft + W_DIM);
    }
}

__global__ __launch_bounds__(BLK) void cc_write(const int* __restrict__ parent,
                                                float* __restrict__ out, int n4) {
    int i = blockIdx.x * blockDim.x + threadIdx.x;
    if (i >= n4) return;
    int4 p = reinterpret_cast<const int4*>(parent)[i];
    int a0 = (p.x >= 0) ? parent[p.x] : 0;
    int a1 = (p.y >= 0) ? parent[p.y] : 0;
    int a2 = (p.z >= 0) ? parent[p.z] : 0;
    int a3 = (p.w >= 0) ? parent[p.w] : 0;
    float4 o;
    { int v = p.x, w = a0; if (v >= 0) { while (w != v) { v = w; w = parent[v]; } }
      o.x = (p.x < 0) ? 0.f : (float)(MULT - (v & (MULT - 1))); }
    { int v = p.y, w = a1; if (v >= 0) { while (w != v) { v = w; w = parent[v]; } }
      o.y = (p.y < 0) ? 0.f : (float)(MULT - (v & (MULT - 1))); }
    { int v = p.z, w = a2; if (v >= 0) { while (w != v) { v = w; w = parent[v]; } }
      o.z = (p.z < 0) ? 0.f : (float)(MULT - (v & (MULT - 1))); }
    { int v = p.w, w = a3; if (v >= 0) { while (w != v) { v = w; w = parent[v]; } }
      o.w = (p.w < 0) ? 0.f : (float)(MULT - (v & (MULT - 1))); }
    reinterpret_cast<float4*>(out)[i] = o;
}

__global__ __launch_bounds__(BLK) void cc_flatten(int* __restrict__ parent, int n) {
    int i = blockIdx.x * blockDim.x + threadIdx.x;
    if (i >= n) return;
    int p = parent[i];
    if (p < 0 || p == i) return;
    int r = find_root(parent, p);
    if (r != p) parent[i] = r;
}

__global__ __launch_bounds__(BLK) void cc_final_inplace(int* __restrict__ parent, int n4) {
    int i = blockIdx.x * blockDim.x + threadIdx.x;
    if (i >= n4) return;
    int4 p = reinterpret_cast<const int4*>(parent)[i];
    float4 o;
    o.x = (p.x < 0) ? 0.f : (float)(MULT - (p.x & (MULT - 1)));
    o.y = (p.y < 0) ? 0.f : (float)(MULT - (p.y & (MULT - 1)));
    o.z = (p.z < 0) ? 0.f : (float)(MULT - (p.z & (MULT - 1)));
    o.w = (p.w < 0) ? 0.f : (float)(MULT - (p.w & (MULT - 1)));
    reinterpret_cast<float4*>(parent)[i] = o;
}

extern "C" void kernel_launch(void* const* d_in, const int* in_sizes, int n_in,
                              void* d_out, int out_size, void* d_ws, size_t ws_size,
                              hipStream_t stream) {
    const float* x = (const float*)d_in[0];
    const int n     = in_sizes[0];          // B*H*W
    const int n_img = n / MULT;
    const int n4    = n / 4;
    const int tiles = n_img * TILES_PER_IMG;
    const int border_threads = n_img * 2 * NB * W_DIM;

    // fused-path workspace layout
    size_t off_parent = 0;
    size_t off_bitmap = off_parent + (size_t)n * 4;
    size_t off_slabs  = off_bitmap + (size_t)n / 8;
    size_t off_cnt    = off_slabs  + (size_t)tiles * WCAP * 8;
    size_t off_ovf    = off_cnt    + (size_t)tiles * 4;
    size_t off_ovfcnt = off_ovf    + (size_t)OVF_CAP * 8;
    size_t need_fused = off_ovfcnt + 128;

    dim3 blk(BLK);
    if (ws_size >= need_fused) {
        char* ws = (char*)d_ws;
        int*  parent  = (int*)(ws + off_parent);
        unsigned long long* bitmap = (unsigned long long*)(ws + off_bitmap);
        int2* slabs   = (int2*)(ws + off_slabs);
        int*  wl_cnt  = (int*)(ws + off_cnt);
        int2* ovf     = (int2*)(ws + off_ovf);
        int*  ovf_cnt = (int*)(ws + off_ovfcnt);
        float* out    = (float*)d_out;

        hipMemsetAsync(ovf_cnt, 0, sizeof(int), stream);
        cc_local<1><<<tiles, blk, 0, stream>>>(x, parent, out, bitmap,
                                               slabs, wl_cnt, ovf, ovf_cnt);
        cc_border_bm<<<(border_threads + BLK - 1) / BLK, blk, 0, stream>>>(bitmap, parent, border_threads);
        int fix_threads = tiles * WCAP + OVF_CAP;
        cc_fixup<<<(fix_threads + BLK - 1) / BLK, blk, 0, stream>>>(slabs, wl_cnt, ovf, ovf_cnt,
                                                                    parent, out, tiles);
    } else {
        const bool use_ws = (ws_size >= (size_t)n * sizeof(int));
        int* parent = use_ws ? (int*)d_ws : (int*)d_out;
        cc_local<0><<<tiles, blk, 0, stream>>>(x, parent, nullptr, nullptr,
                                               nullptr, nullptr, nullptr, nullptr);
        cc_border<<<(border_threads + BLK - 1) / BLK, blk, 0, stream>>>(parent, border_threads);
        if (use_ws) {
            cc_write<<<(n4 + BLK - 1) / BLK, blk, 0, stream>>>(parent, (float*)d_out, n4);
        } else {
            cc_flatten      <<<(n + BLK - 1) / BLK, blk, 0, stream>>>(parent, n);
            cc_final_inplace<<<(n4 + BLK - 1) / BLK, blk, 0, stream>>>(parent, n4);
        }
    }
}

// Round 10
// 60.064 us; speedup vs baseline: 1.7098x; 1.0060x over previous
//
#include <hip/hip_runtime.h>

// Two-level connected components, fused output.
//  - cc_local: per-tile union-find in LDS. lp is initialized to per-row RUN
//    STARTS (computed from ballot row masks in registers), so horizontal
//    connectivity needs no merges at all and all trees start flat; the
//    batched drain handles only up/up-left/up-right edges. Border-component
//    roots are flagged in lp (bit 16); Phase C's root walk picks the flag up
//    for free and appends flagged pixels to a per-tile worklist. Final
//    labels stream to out.
//  - cc_border_bm: cross-tile merges; fg tests from a 2MB bitmap,
//    union-find on the sparse parent (endpoints = strip pixels + roots).
//  - cc_fixup: walks worklist entries only (~1.5% of pixels), rewrites
//    labels whose root changed.
//
// Label semantics: out = MULT - min(local linear index over 8-conn component)
// for foreground, 0 for background.
//
// UF invariant: parent[v] <= v, every stored value is a true ancestor ->
// atomicMin linking converges to exact min-index roots (verified r1-r9).
// Run-start init preserves it: run start is connected to p and <= p.
// lp encoding: low 16 bits = parent (0..4095); bit 16 = border flag, set
// ONLY on final roots (after the drain barrier, before Phase C).

constexpr int W_DIM = 2048;
constexpr int H_DIM = 2048;
constexpr int MULT  = W_DIM * H_DIM;        // 2^22 pixels per image
constexpr int TILE  = 64;
constexpr int TPX   = TILE * TILE;          // 4096 pixels per tile
constexpr int BLK   = 256;                  // 4 waves
constexpr int TILES_PER_IMG = MULT / TPX;   // 1024
constexpr int NB    = (H_DIM / TILE) - 1;   // 31 interior boundaries per dim
constexpr int WCAP  = 512;                  // per-tile worklist capacity
constexpr int OVF_CAP = 65536;              // global overflow capacity
constexpr int PMASK = 0xFFFF;               // lp parent field
constexpr int BFLAG = 0x10000;              // lp border flag (roots only)

__device__ __forceinline__ int find_root(const int* p, int v) {
    int q = p[v];
    while (q != v) { v = q; q = p[v]; }
    return v;
}

// flag-tolerant find (marking pass: flags may appear concurrently on roots)
__device__ __forceinline__ int find_root_m(const int* p, int v) {
    int q = p[v] & PMASK;
    while (q != v) { v = q; q = p[v] & PMASK; }
    return v;
}

__device__ __forceinline__ void merge_uf(int* p, int a, int b) {
    while (true) {
        a = find_root(p, a);
        b = find_root(p, b);
        if (a == b) return;
        if (a < b) { int t = a; a = b; b = t; }  // a > b
        int old = atomicMin(&p[a], b);
        if (old == a) return;                    // a was root; linked under b
        a = old;                                 // displaced; retry from old
    }
}

// MODE 0: legacy (write full parent). MODE 1: fused (write out + sparse UF).
template <int MODE>
__global__ __launch_bounds__(BLK) void cc_local(const float* __restrict__ x,
                                                int* __restrict__ parent,
                                                float* __restrict__ out,
                                                unsigned long long* __restrict__ bitmap,
                                                int2* __restrict__ slabs,
                                                int* __restrict__ wl_cnt,
                                                int2* __restrict__ ovf,
                                                int* __restrict__ ovf_cnt) {
    __shared__ int lp[TPX];
    __shared__ unsigned long long rowmask_sh[TILE];
    __shared__ int cursor;

    const int t    = threadIdx.x;
    const int wave = t >> 6;                 // 0..3
    const int lane = t & 63;
    const int tile = blockIdx.x;
    const int img  = tile / TILES_PER_IMG;
    const int tl   = tile % TILES_PER_IMG;
    const int tr   = tl >> 5;                // 32 tile cols per image row
    const int tc   = tl & 31;
    const int origin    = img * MULT + (tr * TILE) * W_DIM + tc * TILE;
    const int img_base  = img * MULT;
    const int base_loc  = origin - img_base; // tile origin, local-in-image

    // ---- Phase A: load x, ballot row bitmaps, run-start lp init ----
    unsigned long long m[16];
    #pragma unroll
    for (int rr = 0; rr < 16; ++rr) {
        int row = wave * 16 + rr;
        float v = x[origin + row * W_DIM + lane];
        m[rr] = __ballot(v != 0.0f);
    }
    const unsigned long long lanebit_m1 = (1ULL << lane) - 1ULL;
    #pragma unroll
    for (int rr = 0; rr < 16; ++rr) {
        int row = wave * 16 + rr;
        unsigned long long mm = m[rr];
        unsigned long long below = ~mm & lanebit_m1;   // bg positions below lane
        int start = below ? (64 - __clzll(below)) : 0; // run start for fg pixels
        bool fg = (mm >> lane) & 1ULL;
        lp[row * TILE + lane] = row * TILE + (fg ? start : lane);
    }
    if (lane == 0) {
        #pragma unroll
        for (int rr = 0; rr < 16; ++rr) rowmask_sh[wave * 16 + rr] = m[rr];
    }
    if constexpr (MODE == 1) {
        if (t == 0) cursor = 0;
    }
    __syncthreads();

    // bitmap export: one wave-wide store (lane = row), masks from LDS.
    if constexpr (MODE == 1) {
        if (wave == 0) {
            int grow = tr * TILE + lane;
            bitmap[(img * H_DIM + grow) * (W_DIM / 64) + tc] = rowmask_sh[lane];
        }
    }

    const unsigned long long mu0 = (wave > 0) ? rowmask_sh[wave * 16 - 1] : 0ULL;

    // ---- Phase B1: per-lane merge bitset (bit 4*rr+type; type 0 unused —
    // left connectivity comes from run-start init) ----
    unsigned long long bits = 0ULL;
    #pragma unroll
    for (int rr = 0; rr < 16; ++rr) {
        const unsigned long long mm = m[rr];
        const unsigned long long mu = (rr == 0) ? mu0 : m[rr - 1];
        const unsigned long long bfmask = mm & mu & ~((mm << 1) & (mu << 1));
        const unsigned long long afmask = mm & (mu << 1) & ~mu & ~(mm << 1);
        const unsigned long long cfmask = mm & (mu >> 1) & ~mu;
        unsigned nib = ((unsigned)((bfmask >> lane) & 1ULL) << 1)
                     | ((unsigned)((afmask >> lane) & 1ULL) << 2)
                     | ((unsigned)((cfmask >> lane) & 1ULL) << 3);
        bits |= (unsigned long long)nib << (rr * 4);
    }

    // ---- Phase B2: batched merge drain (no flags exist yet) ----
    while (__any(bits != 0ULL)) {
        if (bits) {
            int idx = (int)__builtin_ctzll(bits);
            bits &= bits - 1;
            int rr = idx >> 2, ty = idx & 3;
            int p  = (wave * 16 + rr) * TILE + lane;
            int off = (ty & 2) ? ((ty & 1) ? -(TILE - 1) : -(TILE + 1))
                               : ((ty & 1) ? -TILE : -1);
            merge_uf(lp, p, p + off);
        }
    }
    __syncthreads();

    // ---- Marking (MODE 1): wave-parallel strip marking. Flag the root in
    // lp (bit 16) and seed the sparse global parent (pixel + root). ----
    if constexpr (MODE == 1) {
        int p = -1;
        bool mark = false;
        if      (wave == 0) { if (tr > 0)  { p = lane;                      mark = (rowmask_sh[0]    >> lane) & 1ULL; } }
        else if (wave == 3) { if (tr < 31) { p = (TILE - 1) * TILE + lane;  mark = (rowmask_sh[63]   >> lane) & 1ULL; } }
        else if (wave == 1) { if (tc > 0)  { p = lane * TILE;               mark = rowmask_sh[lane] & 1ULL; } }
        else                { if (tc < 31) { p = lane * TILE + (TILE - 1);  mark = (rowmask_sh[lane] >> 63) & 1ULL; } }
        if (mark) {
            int v = find_root_m(lp, p);
            atomicOr(&lp[v], BFLAG);
            int rg = origin + (v >> 6) * W_DIM + (v & (TILE - 1));
            int pg = origin + (p >> 6) * W_DIM + (p & (TILE - 1));
            parent[pg] = rg;
            parent[rg] = rg;
        }
        __syncthreads();
    }

    // ---- Phase C: root walk (flag rides the final read), write labels
    // (MODE1) or parent (MODE0); flagged pixels append inline. ----
    #pragma unroll
    for (int j = 0; j < 4; ++j) {
        int s   = t + BLK * j;               // int4 slot in tile
        int row = s >> 4;
        int c4  = s & 15;
        int p0  = row * TILE + c4 * 4;
        int4 qv = reinterpret_cast<const int4*>(lp)[s];
        unsigned fgbits = (unsigned)((rowmask_sh[row] >> (c4 * 4)) & 0xFULL);
        int vr[4], qf[4];
        {
            int q = qv.x, v = q & PMASK, p = p0;
            if ((fgbits & 1u) && v != p) {
                int w = lp[v];
                while ((w & PMASK) != v) { v = w & PMASK; w = lp[v]; }
                q = w;
            }
            vr[0] = v; qf[0] = q;
        }
        {
            int q = qv.y, v = q & PMASK, p = p0 + 1;
            if ((fgbits & 2u) && v != p) {
                int w = lp[v];
                while ((w & PMASK) != v) { v = w & PMASK; w = lp[v]; }
                q = w;
            }
            vr[1] = v; qf[1] = q;
        }
        {
            int q = qv.z, v = q & PMASK, p = p0 + 2;
            if ((fgbits & 4u) && v != p) {
                int w = lp[v];
                while ((w & PMASK) != v) { v = w & PMASK; w = lp[v]; }
                q = w;
            }
            vr[2] = v; qf[2] = q;
        }
        {
            int q = qv.w, v = q & PMASK, p = p0 + 3;
            if ((fgbits & 8u) && v != p) {
                int w = lp[v];
                while ((w & PMASK) != v) { v = w & PMASK; w = lp[v]; }
                q = w;
            }
            vr[3] = v; qf[3] = q;
        }

        if constexpr (MODE == 0) {
            int4 o;
            o.x = (fgbits & 1u) ? origin + (vr[0] >> 6) * W_DIM + (vr[0] & (TILE - 1)) : -1;
            o.y = (fgbits & 2u) ? origin + (vr[1] >> 6) * W_DIM + (vr[1] & (TILE - 1)) : -1;
            o.z = (fgbits & 4u) ? origin + (vr[2] >> 6) * W_DIM + (vr[2] & (TILE - 1)) : -1;
            o.w = (fgbits & 8u) ? origin + (vr[3] >> 6) * W_DIM + (vr[3] & (TILE - 1)) : -1;
            reinterpret_cast<int4*>(parent + origin + row * W_DIM)[c4] = o;
        } else {
            float lab[4];
            #pragma unroll
            for (int k = 0; k < 4; ++k) {
                int v  = vr[k];
                bool fg = (fgbits >> k) & 1u;
                int rl = base_loc + ((v >> 6) << 11) + (v & (TILE - 1)); // root, local-in-image
                lab[k] = fg ? (float)(MULT - rl) : 0.0f;
                if (fg && (qf[k] & BFLAG)) {                 // border component
                    int off = atomicAdd(&cursor, 1);
                    int pg  = origin + row * W_DIM + c4 * 4 + k;
                    int g   = img_base + rl;
                    if (off < WCAP) slabs[tile * WCAP + off] = make_int2(pg, g);
                    else {
                        int oi = atomicAdd(ovf_cnt, 1);
                        if (oi < OVF_CAP) ovf[oi] = make_int2(pg, g);
                    }
                }
            }
            float4 o; o.x = lab[0]; o.y = lab[1]; o.z = lab[2]; o.w = lab[3];
            reinterpret_cast<float4*>(out + origin + row * W_DIM)[c4] = o;
        }
    }

    if constexpr (MODE == 1) {
        __syncthreads();
        if (t == 0) wl_cnt[tile] = (cursor < WCAP) ? cursor : WCAP;
    }
}

// Cross-tile merges; fg from bitmap, UF on sparse parent (endpoints are
// strip pixels -> initialized by cc_local's marking pass).
__global__ __launch_bounds__(BLK) void cc_border_bm(const unsigned long long* __restrict__ bm,
                                                    int* __restrict__ parent, int total) {
    int tid = blockIdx.x * blockDim.x + threadIdx.x;
    if (tid >= total) return;
    const int per_img = 2 * NB * W_DIM;
    int img = tid / per_img;
    int k   = tid % per_img;
    int base = img * MULT;
    const unsigned long long* b = bm + (size_t)img * H_DIM * (W_DIM / 64);
    auto FG = [&](int r, int c) -> bool {
        return (b[r * (W_DIM / 64) + (c >> 6)] >> (c & 63)) & 1ULL;
    };
    if (k < NB * W_DIM) {
        int r = TILE * (1 + k / W_DIM);
        int c = k % W_DIM;
        if (!FG(r, c)) return;
        int i  = base + r * W_DIM + c;
        int up = i - W_DIM;
        if (FG(r - 1, c))                      merge_uf(parent, i, up);
        if (c > 0         && FG(r - 1, c - 1)) merge_uf(parent, i, up - 1);
        if (c < W_DIM - 1 && FG(r - 1, c + 1)) merge_uf(parent, i, up + 1);
    } else {
        int m2 = k - NB * W_DIM;
        int c = TILE * (1 + m2 / H_DIM);
        int r = m2 % H_DIM;
        if (!FG(r, c)) return;
        int i   = base + r * W_DIM + c;
        int lft = i - 1;
        if (FG(r, c - 1))                      merge_uf(parent, i, lft);
        if (r > 0         && FG(r - 1, c - 1)) merge_uf(parent, i, lft - W_DIM);
        if (r < H_DIM - 1 && FG(r + 1, c - 1)) merge_uf(parent, i, lft + W_DIM);
    }
}

// Rewrite labels of border-component pixels whose root changed.
__global__ __launch_bounds__(BLK) void cc_fixup(const int2* __restrict__ slabs,
                                                const int* __restrict__ wl_cnt,
                                                const int2* __restrict__ ovf,
                                                const int* __restrict__ ovf_cnt,
                                                const int* __restrict__ parent,
                                                float* __restrict__ out, int ntiles) {
    int tid = blockIdx.x * blockDim.x + threadIdx.x;
    int slab_total = ntiles * WCAP;
    int2 e;
    if (tid < slab_total) {
        int tile = tid / WCAP, slot = tid - tile * WCAP;
        if (slot >= wl_cnt[tile]) return;
        e = slabs[tid];
    } else {
        int oi = tid - slab_total;
        int oc = *ovf_cnt; if (oc > OVF_CAP) oc = OVF_CAP;
        if (oi >= oc) return;
        e = ovf[oi];
    }
    int root = find_root(parent, e.y);
    if (root != e.y) out[e.x] = (float)(MULT - (root & (MULT - 1)));
}

// ---------------- legacy fallback kernels ----------------
__global__ __launch_bounds__(BLK) void cc_border(int* __restrict__ parent, int total) {
    int tid = blockIdx.x * blockDim.x + threadIdx.x;
    if (tid >= total) return;
    const int per_img = 2 * NB * W_DIM;
    int img = tid / per_img;
    int k   = tid % per_img;
    int base = img * MULT;
    if (k < NB * W_DIM) {
        int r = TILE * (1 + k / W_DIM);
        int c = k % W_DIM;
        int i = base + r * W_DIM + c;
        if (parent[i] < 0) return;
        int up = i - W_DIM;
        if (parent[up] >= 0)                      merge_uf(parent, i, up);
        if (c > 0         && parent[up - 1] >= 0) merge_uf(parent, i, up - 1);
        if (c < W_DIM - 1 && parent[up + 1] >= 0) merge_uf(parent, i, up + 1);
    } else {
        int m2 = k - NB * W_DIM;
        int c = TILE * (1 + m2 / H_DIM);
        int r = m2 % H_DIM;
        int i = base + r * W_DIM + c;
        if (parent[i] < 0) return;
        int lft = i - 1;
        if (parent[lft] >= 0)                            merge_uf(parent, i, lft);
        if (r > 0         && parent[lft - W_DIM] >= 0)   merge_uf(parent, i, lft - W_DIM);
        if (r < H_DIM - 1 && parent[lft + W_DIM] >= 0)   merge_uf(parent, i, lft + W_DIM);
    }
}

__global__ __launch_bounds__(BLK) void cc_write(const int* __restrict__ parent,
                                                float* __restrict__ out, int n4) {
    int i = blockIdx.x * blockDim.x + threadIdx.x;
    if (i >= n4) return;
    int4 p = reinterpret_cast<const int4*>(parent)[i];
    int a0 = (p.x >= 0) ? parent[p.x] : 0;
    int a1 = (p.y >= 0) ? parent[p.y] : 0;
    int a2 = (p.z >= 0) ? parent[p.z] : 0;
    int a3 = (p.w >= 0) ? parent[p.w] : 0;
    float4 o;
    { int v = p.x, w = a0; if (v >= 0) { while (w != v) { v = w; w = parent[v]; } }
      o.x = (p.x < 0) ? 0.f : (float)(MULT - (v & (MULT - 1))); }
    { int v = p.y, w = a1; if (v >= 0) { while (w != v) { v = w; w = parent[v]; } }
      o.y = (p.y < 0) ? 0.f : (float)(MULT - (v & (MULT - 1))); }
    { int v = p.z, w = a2; if (v >= 0) { while (w != v) { v = w; w = parent[v]; } }
      o.z = (p.z < 0) ? 0.f : (float)(MULT - (v & (MULT - 1))); }
    { int v = p.w, w = a3; if (v >= 0) { while (w != v) { v = w; w = parent[v]; } }
      o.w = (p.w < 0) ? 0.f : (float)(MULT - (v & (MULT - 1))); }
    reinterpret_cast<float4*>(out)[i] = o;
}

__global__ __launch_bounds__(BLK) void cc_flatten(int* __restrict__ parent, int n) {
    int i = blockIdx.x * blockDim.x + threadIdx.x;
    if (i >= n) return;
    int p = parent[i];
    if (p < 0 || p == i) return;
    int r = find_root(parent, p);
    if (r != p) parent[i] = r;
}

__global__ __launch_bounds__(BLK) void cc_final_inplace(int* __restrict__ parent, int n4) {
    int i = blockIdx.x * blockDim.x + threadIdx.x;
    if (i >= n4) return;
    int4 p = reinterpret_cast<const int4*>(parent)[i];
    float4 o;
    o.x = (p.x < 0) ? 0.f : (float)(MULT - (p.x & (MULT - 1)));
    o.y = (p.y < 0) ? 0.f : (float)(MULT - (p.y & (MULT - 1)));
    o.z = (p.z < 0) ? 0.f : (float)(MULT - (p.z & (MULT - 1)));
    o.w = (p.w < 0) ? 0.f : (float)(MULT - (p.w & (MULT - 1)));
    reinterpret_cast<float4*>(parent)[i] = o;
}

extern "C" void kernel_launch(void* const* d_in, const int* in_sizes, int n_in,
                              void* d_out, int out_size, void* d_ws, size_t ws_size,
                              hipStream_t stream) {
    const float* x = (const float*)d_in[0];
    const int n     = in_sizes[0];          // B*H*W
    const int n_img = n / MULT;
    const int n4    = n / 4;
    const int tiles = n_img * TILES_PER_IMG;
    const int border_threads = n_img * 2 * NB * W_DIM;

    // fused-path workspace layout
    size_t off_parent = 0;
    size_t off_bitmap = off_parent + (size_t)n * 4;
    size_t off_slabs  = off_bitmap + (size_t)n / 8;
    size_t off_cnt    = off_slabs  + (size_t)tiles * WCAP * 8;
    size_t off_ovf    = off_cnt    + (size_t)tiles * 4;
    size_t off_ovfcnt = off_ovf    + (size_t)OVF_CAP * 8;
    size_t need_fused = off_ovfcnt + 128;

    dim3 blk(BLK);
    if (ws_size >= need_fused) {
        char* ws = (char*)d_ws;
        int*  parent  = (int*)(ws + off_parent);
        unsigned long long* bitmap = (unsigned long long*)(ws + off_bitmap);
        int2* slabs   = (int2*)(ws + off_slabs);
        int*  wl_cnt  = (int*)(ws + off_cnt);
        int2* ovf     = (int2*)(ws + off_ovf);
        int*  ovf_cnt = (int*)(ws + off_ovfcnt);
        float* out    = (float*)d_out;

        hipMemsetAsync(ovf_cnt, 0, sizeof(int), stream);
        cc_local<1><<<tiles, blk, 0, stream>>>(x, parent, out, bitmap,
                                               slabs, wl_cnt, ovf, ovf_cnt);
        cc_border_bm<<<(border_threads + BLK - 1) / BLK, blk, 0, stream>>>(bitmap, parent, border_threads);
        int fix_threads = tiles * WCAP + OVF_CAP;
        cc_fixup<<<(fix_threads + BLK - 1) / BLK, blk, 0, stream>>>(slabs, wl_cnt, ovf, ovf_cnt,
                                                                    parent, out, tiles);
    } else {
        const bool use_ws = (ws_size >= (size_t)n * sizeof(int));
        int* parent = use_ws ? (int*)d_ws : (int*)d_out;
        cc_local<0><<<tiles, blk, 0, stream>>>(x, parent, nullptr, nullptr,
                                               nullptr, nullptr, nullptr, nullptr);
        cc_border<<<(border_threads + BLK - 1) / BLK, blk, 0, stream>>>(parent, border_threads);
        if (use_ws) {
            cc_write<<<(n4 + BLK - 1) / BLK, blk, 0, stream>>>(parent, (float*)d_out, n4);
        } else {
            cc_flatten      <<<(n + BLK - 1) / BLK, blk, 0, stream>>>(parent, n);
            cc_final_inplace<<<(n4 + BLK - 1) / BLK, blk, 0, stream>>>(parent, n4);
        }
    }
}